// Round 4
// baseline (622.104 us; speedup 1.0000x reference)
//
#include <hip/hip_runtime.h>
#include <hip/hip_cooperative_groups.h>
#include <math.h>

namespace cg = cooperative_groups;

#define N_NODES 20000
#define N_EDGES 320000
#define C_IN  256
#define C_HID 256
#define C_OUT 128
#define NEG_SLOPE 0.2f
#define CAP   256   // padded-CSR slots per node (real edges only; self-loop implicit)
#define GEMM1_BLKS (N_NODES / 32)          // 625
#define SCAT_BLKS  ((N_EDGES + 255) / 256) // 1250
#define AGGEMM_BLKS (N_NODES / 16)         // 1250
#define AGG2_BLKS  (N_NODES / 4)           // 5000
#define AGG_PAD 280 // 256 + 24: LDS row stride (560 B = 16B-aligned, 8 bank-start groups)

typedef __attribute__((ext_vector_type(8))) short bf16x8;
typedef __attribute__((ext_vector_type(4))) float f32x4;

// ---- all scratch in module globals (ws_size unknown; globals are safe) ----
__device__ __align__(16) unsigned short c_W1h[C_IN * C_HID], c_W1l[C_IN * C_HID];
__device__ __align__(16) unsigned short c_W2h[C_HID * C_OUT], c_W2l[C_HID * C_OUT];
__device__ float c_as1f[C_HID], c_ad1f[C_HID], c_b1f[C_HID];
__device__ float c_as2f[C_OUT], c_ad2f[C_OUT], c_b2f[C_OUT];
__device__ __align__(16) unsigned short g_h1b[(size_t)N_NODES * C_HID]; // h1 bf16
__device__ __align__(16) unsigned short g_h2b[(size_t)N_NODES * C_OUT]; // h2 bf16
__device__ float g_alps1[N_NODES], g_alpd1[N_NODES];
__device__ float g_alps2[N_NODES], g_alpd2[N_NODES];
__device__ int   g_cursor[N_NODES];            // per-node real-edge count
__device__ int   g_srcidx[(size_t)N_NODES * CAP];
__device__ int   g_is64;    // edge_index arrived as raw int64 words (fallback path)
__device__ int   g_isf32;   // float inputs arrived as raw fp32 words (fallback path)
__device__ int   g_q1, g_q2, g_q3;  // dynamic virtual-block queues (coop kernel)

__device__ __forceinline__ float bf2f(unsigned short b){
  unsigned int u = ((unsigned int)b) << 16;
  return __builtin_bit_cast(float, u);
}
__device__ __forceinline__ unsigned short f2bf(float f){
  unsigned int u = __builtin_bit_cast(unsigned int, f);
  u += 0x7fffu + ((u >> 16) & 1u);   // round-to-nearest-even
  return (unsigned short)(u >> 16);
}
__device__ __forceinline__ int clampi(int v){
  v = v < 0 ? 0 : v;
  return v >= N_NODES ? N_NODES - 1 : v;
}

struct Ptrs { const void* p[8]; };

// pack (k, n) of a [K][Nc] weight into MFMA B-fragment order
__device__ __forceinline__ int wpack(int k, int n, int Nc){
  return (((k >> 5) * (Nc / 16) + (n >> 4)) * 64 + (((k >> 3) & 3) * 16 + (n & 15))) * 8 + (k & 7);
}

#define PREP_Z  N_NODES
#define PREP_W1 (C_IN * C_HID)
#define PREP_W2 (C_HID * C_OUT)
#define PREP_T  (PREP_Z + PREP_W1 + PREP_W2 + 2 * C_HID + C_HID + 2 * C_OUT + C_OUT)

#define ACC4(p, ww) { \
  a0 += (ww) * bf2f((unsigned short)((p).x & 0xFFFFu)); \
  a1 += (ww) * bf2f((unsigned short)((p).x >> 16)); \
  a2 += (ww) * bf2f((unsigned short)((p).y & 0xFFFFu)); \
  a3 += (ww) * bf2f((unsigned short)((p).y >> 16)); }

#define ACC2(p, ww) { \
  a0 += (ww) * bf2f((unsigned short)((p) & 0xFFFFu)); \
  a1 += (ww) * bf2f((unsigned short)((p) >> 16)); }

// =======================================================================
// fused_k: ALL FIVE PHASES in one cooperative dispatch.
//   P0 prep (probe + cursor zero + weight pack)  -> grid.sync
//   P1 gemm1 tiles + edge scatter (dynamic queue) -> grid.sync
//   P2 agg1+gemm2 fused tiles (dynamic queue)     -> grid.sync
//   P3 agg2 (dynamic queue)
// Removes 4 dispatch boundaries (launch + device drain each). Dynamic
// queues load-balance any co-resident grid size. __threadfence before
// each grid sync: agent-scope fence -> cross-XCD L2 writeback/inv.
// =======================================================================
__global__ __launch_bounds__(256, 4) void fused_k(const unsigned int* __restrict__ xw,
                                                  const int* __restrict__ ei,
                                                  float* __restrict__ OUT,
                                                  Ptrs ps){
  __shared__ __align__(16) unsigned short s_hi[16 * AGG_PAD];
  __shared__ __align__(16) unsigned short s_lo[16 * AGG_PAD];
  __shared__ float s_ps[4][32], s_pd[4][32];
  __shared__ int s_flags, s_vb;

  const int tidx = (int)threadIdx.x;
  const int lane = tidx & 63;
  const int wid  = tidx >> 6;

  // ---------------- phase 0: probe + cursor zero + weight pack ----------------
  if (tidx < 64){
    int cnt = 0;
    for (int j = lane; j < 256; j += 64){
      unsigned int e = (xw[j] >> 7) & 0xFFu;
      if (e >= 0x60u && e <= 0x8Fu) ++cnt;
    }
#pragma unroll
    for (int o = 32; o > 0; o >>= 1) cnt += __shfl_xor(cnt, o, 64);
    unsigned long long anybad = __ballot(ei[2 * lane + 1] != 0);
    if (lane == 0) s_flags = ((cnt < 200) ? 1 : 0) | ((anybad == 0ULL) ? 2 : 0);
  }
  if (blockIdx.x == 0 && tidx == 0){ g_q1 = 0; g_q2 = 0; g_q3 = 0; }
  __syncthreads();
  const bool isf32 = (s_flags & 1) != 0;
  const bool is64  = (s_flags & 2) != 0;

  const int total = (int)(gridDim.x * blockDim.x);
  auto ld = [&](const void* p, int i) -> float {
    return isf32 ? ((const float*)p)[i] : bf2f(((const unsigned short*)p)[i]);
  };
  for (int t = (int)(blockIdx.x * blockDim.x) + tidx; t < PREP_T; t += total){
    if (t < PREP_Z){ g_cursor[t] = 0; continue; }
    int j = t - PREP_Z;
    if (j < PREP_W1){
      float f = ld(ps.p[0], j);
      int k = j / C_HID, n = j % C_HID;
      int idx = wpack(k, n, C_HID);
      unsigned short h = f2bf(f);
      c_W1h[idx] = h; c_W1l[idx] = f2bf(f - bf2f(h));
      continue;
    }
    j -= PREP_W1;
    if (j < PREP_W2){
      float f = ld(ps.p[4], j);
      int k = j / C_OUT, n = j % C_OUT;
      int idx = wpack(k, n, C_OUT);
      unsigned short h = f2bf(f);
      c_W2h[idx] = h; c_W2l[idx] = f2bf(f - bf2f(h));
      continue;
    }
    j -= PREP_W2;
    if      (j <  256) c_as1f[j]        = ld(ps.p[1], j);
    else if (j <  512) c_ad1f[j - 256]  = ld(ps.p[2], j - 256);
    else if (j <  768) c_b1f [j - 512]  = ld(ps.p[3], j - 512);
    else if (j <  896) c_as2f[j - 768]  = ld(ps.p[5], j - 768);
    else if (j < 1024) c_ad2f[j - 896]  = ld(ps.p[6], j - 896);
    else if (j < 1152) c_b2f [j - 1024] = ld(ps.p[7], j - 1024);
  }

  __threadfence();
  cg::this_grid().sync();

  // ---------------- phase 1: gemm1 tiles + edge scatter (queue) ----------------
  for (;;){
    __syncthreads();                       // protects s_vb / s_ps from prev iter
    if (tidx == 0) s_vb = atomicAdd(&g_q1, 1);
    __syncthreads();
    const int vb = s_vb;
    if (vb >= GEMM1_BLKS + SCAT_BLKS) break;

    if (vb >= GEMM1_BLKS){                 // ---- scatter chunk ----
      int e = (vb - GEMM1_BLKS) * 256 + tidx;
      if (e < N_EDGES){
        int s, d;
        if (is64){ s = ei[2 * e]; d = ei[2 * (N_EDGES + e)]; }
        else     { s = ei[e];     d = ei[N_EDGES + e]; }
        s = clampi(s); d = clampi(d);
        int pos = atomicAdd(&g_cursor[d], 1);
        if (pos < CAP) g_srcidx[(size_t)d * CAP + pos] = s;
      }
      continue;
    }

    // ---- gemm1 tile: rows [vb*32, vb*32+32), all 256 cols ----
    int kgrp = lane >> 4, cl = lane & 15;
    int mbase = vb * 32;
    f32x4 acc[2][4];
#pragma unroll
    for (int m = 0; m < 2; ++m)
#pragma unroll
      for (int n = 0; n < 4; ++n) acc[m][n] = (f32x4){0.f, 0.f, 0.f, 0.f};

    for (int kt = 0; kt < 8; ++kt){
      int kbase = kt * 32 + kgrp * 8;
      bf16x8 ah[2], al[2];
      if (isf32){
        const float* Xf = (const float*)xw;
#pragma unroll
        for (int m = 0; m < 2; ++m){
          const float4* xp = (const float4*)(Xf + (size_t)(mbase + m * 16 + cl) * 256 + kbase);
          float4 v0 = xp[0], v1 = xp[1];
          float vals[8] = {v0.x, v0.y, v0.z, v0.w, v1.x, v1.y, v1.z, v1.w};
#pragma unroll
          for (int j = 0; j < 8; ++j){
            unsigned short h = f2bf(vals[j]);
            ah[m][j] = (short)h;
            al[m][j] = (short)f2bf(vals[j] - bf2f(h));
          }
        }
      } else {
        const unsigned short* Xb = (const unsigned short*)xw;
#pragma unroll
        for (int m = 0; m < 2; ++m){
          ah[m] = *(const bf16x8*)(Xb + (size_t)(mbase + m * 16 + cl) * 256 + kbase);
          al[m] = (bf16x8){0,0,0,0,0,0,0,0};
        }
      }
#pragma unroll
      for (int nn = 0; nn < 4; ++nn){
        int nt = wid * 4 + nn;
        size_t wi = ((size_t)(kt * 16 + nt) * 64 + lane) * 8;   // Nc/16 = 16
        bf16x8 bh = *(const bf16x8*)(c_W1h + wi);
        bf16x8 bl = *(const bf16x8*)(c_W1l + wi);
#pragma unroll
        for (int m = 0; m < 2; ++m){
          acc[m][nn] = __builtin_amdgcn_mfma_f32_16x16x32_bf16(ah[m], bh, acc[m][nn], 0, 0, 0);
          acc[m][nn] = __builtin_amdgcn_mfma_f32_16x16x32_bf16(ah[m], bl, acc[m][nn], 0, 0, 0);
          acc[m][nn] = __builtin_amdgcn_mfma_f32_16x16x32_bf16(al[m], bh, acc[m][nn], 0, 0, 0);
        }
      }
    }

    float asv[4], adv[4];
#pragma unroll
    for (int nn = 0; nn < 4; ++nn){
      int col = (wid * 4 + nn) * 16 + cl;
      asv[nn] = c_as1f[col]; adv[nn] = c_ad1f[col];
    }
#pragma unroll
    for (int m = 0; m < 2; ++m){
#pragma unroll
      for (int i = 0; i < 4; ++i){
        int rl = m * 16 + kgrp * 4 + i;
        int row = mbase + rl;
        float psum = 0.f, pdum = 0.f;
#pragma unroll
        for (int nn = 0; nn < 4; ++nn){
          int col = (wid * 4 + nn) * 16 + cl;
          float v = acc[m][nn][i];
          g_h1b[(size_t)row * C_HID + col] = f2bf(v);
          psum += v * asv[nn]; pdum += v * adv[nn];
        }
        psum += __shfl_xor(psum, 1);  pdum += __shfl_xor(pdum, 1);
        psum += __shfl_xor(psum, 2);  pdum += __shfl_xor(pdum, 2);
        psum += __shfl_xor(psum, 4);  pdum += __shfl_xor(pdum, 4);
        psum += __shfl_xor(psum, 8);  pdum += __shfl_xor(pdum, 8);
        if (cl == 0){ s_ps[wid][rl] = psum; s_pd[wid][rl] = pdum; }
      }
    }
    __syncthreads();
    if (tidx < 32){
      int r = tidx;
      g_alps1[mbase + r] = s_ps[0][r] + s_ps[1][r] + s_ps[2][r] + s_ps[3][r];
      g_alpd1[mbase + r] = s_pd[0][r] + s_pd[1][r] + s_pd[2][r] + s_pd[3][r];
    }
  }

  __threadfence();
  cg::this_grid().sync();

  // ---------------- phase 2: agg1 + gemm2 fused tiles (queue) ----------------
  for (;;){
    __syncthreads();                       // protects s_vb / s_hi / s_ps
    if (tidx == 0) s_vb = atomicAdd(&g_q2, 1);
    __syncthreads();
    const int vb = s_vb;
    if (vb >= AGGEMM_BLKS) break;
    const int nb = vb * 16;
    const uint2* H2 = (const uint2*)g_h1b;

    // ---- agg: each wave aggregates 4 nodes ----
    for (int q = 0; q < 4; ++q){
      int n = nb + wid * 4 + q;
      int len = g_cursor[n]; if (len > CAP) len = CAP;
      int i0 = n * CAP, i1 = i0 + len;
      float adn = g_alpd1[n];
      float dpart = 0.f;
      float a0 = 0.f, a1 = 0.f, a2 = 0.f, a3 = 0.f;

      { // implicit self-loop
        float es = g_alps1[n] + adn;
        es = (es > 0.f) ? es : NEG_SLOPE * es;
        float wself = __expf(es);
        if (lane == 0) dpart += wself;
        uint2 p = H2[(size_t)n * 64 + lane];
        ACC4(p, wself)
      }

      for (int base = i0; base < i1; base += 64){
        int nv = i1 - base; if (nv > 64) nv = 64;
        int sv = 0; float wv = 0.f;
        if (lane < nv){
          sv = g_srcidx[base + lane];
          float e = g_alps1[sv] + adn;
          e = (e > 0.f) ? e : NEG_SLOPE * e;
          wv = __expf(e);
        }
        dpart += wv;
        int j = 0;
        for (; j + 8 <= nv; j += 8){
          int t0 = __shfl(sv, j),     t1 = __shfl(sv, j + 1);
          int t2 = __shfl(sv, j + 2), t3 = __shfl(sv, j + 3);
          int t4 = __shfl(sv, j + 4), t5 = __shfl(sv, j + 5);
          int t6 = __shfl(sv, j + 6), t7 = __shfl(sv, j + 7);
          float w0 = __shfl(wv, j),     w1 = __shfl(wv, j + 1);
          float w2 = __shfl(wv, j + 2), w3 = __shfl(wv, j + 3);
          float w4 = __shfl(wv, j + 4), w5 = __shfl(wv, j + 5);
          float w6 = __shfl(wv, j + 6), w7 = __shfl(wv, j + 7);
          uint2 p0 = H2[(size_t)t0 * 64 + lane];
          uint2 p1 = H2[(size_t)t1 * 64 + lane];
          uint2 p2 = H2[(size_t)t2 * 64 + lane];
          uint2 p3 = H2[(size_t)t3 * 64 + lane];
          uint2 p4 = H2[(size_t)t4 * 64 + lane];
          uint2 p5 = H2[(size_t)t5 * 64 + lane];
          uint2 p6 = H2[(size_t)t6 * 64 + lane];
          uint2 p7 = H2[(size_t)t7 * 64 + lane];
          ACC4(p0, w0) ACC4(p1, w1) ACC4(p2, w2) ACC4(p3, w3)
          ACC4(p4, w4) ACC4(p5, w5) ACC4(p6, w6) ACC4(p7, w7)
        }
        for (; j + 4 <= nv; j += 4){
          int t0 = __shfl(sv, j),     t1 = __shfl(sv, j + 1);
          int t2 = __shfl(sv, j + 2), t3 = __shfl(sv, j + 3);
          float w0 = __shfl(wv, j),     w1 = __shfl(wv, j + 1);
          float w2 = __shfl(wv, j + 2), w3 = __shfl(wv, j + 3);
          uint2 p0 = H2[(size_t)t0 * 64 + lane];
          uint2 p1 = H2[(size_t)t1 * 64 + lane];
          uint2 p2 = H2[(size_t)t2 * 64 + lane];
          uint2 p3 = H2[(size_t)t3 * 64 + lane];
          ACC4(p0, w0) ACC4(p1, w1) ACC4(p2, w2) ACC4(p3, w3)
        }
        for (; j < nv; ++j){
          int t = __shfl(sv, j);
          float w = __shfl(wv, j);
          uint2 p = H2[(size_t)t * 64 + lane];
          ACC4(p, w)
        }
      }

      float den = dpart;
#pragma unroll
      for (int o = 32; o > 0; o >>= 1) den += __shfl_xor(den, o, 64);
      float inv = 1.f / den;

      float o0 = a0 * inv + c_b1f[4 * lane];
      float o1 = a1 * inv + c_b1f[4 * lane + 1];
      float o2 = a2 * inv + c_b1f[4 * lane + 2];
      float o3 = a3 * inv + c_b1f[4 * lane + 3];
      o0 = fmaxf(o0, 0.f); o1 = fmaxf(o1, 0.f);
      o2 = fmaxf(o2, 0.f); o3 = fmaxf(o3, 0.f);
      unsigned short h0 = f2bf(o0), h1 = f2bf(o1), h2 = f2bf(o2), h3 = f2bf(o3);
      uint2 ph, pl;
      ph.x = (unsigned)h0 | ((unsigned)h1 << 16);
      ph.y = (unsigned)h2 | ((unsigned)h3 << 16);
      pl.x = (unsigned)f2bf(o0 - bf2f(h0)) | ((unsigned)f2bf(o1 - bf2f(h1)) << 16);
      pl.y = (unsigned)f2bf(o2 - bf2f(h2)) | ((unsigned)f2bf(o3 - bf2f(h3)) << 16);
      int r = wid * 4 + q;
      *(uint2*)&s_hi[r * AGG_PAD + 4 * lane] = ph;
      *(uint2*)&s_lo[r * AGG_PAD + 4 * lane] = pl;
    }
    __syncthreads();

    // ---- gemm2 tile: rows [nb, nb+16), cols [0,128), K=256 ----
    int kgrp = lane >> 4, cl = lane & 15;
    f32x4 acc2[2];
    acc2[0] = (f32x4){0.f, 0.f, 0.f, 0.f};
    acc2[1] = (f32x4){0.f, 0.f, 0.f, 0.f};
    for (int kt = 0; kt < 8; ++kt){
      int rb = cl * AGG_PAD + kt * 32 + kgrp * 8;
      bf16x8 ah = *(const bf16x8*)&s_hi[rb];
      bf16x8 al = *(const bf16x8*)&s_lo[rb];
#pragma unroll
      for (int nn = 0; nn < 2; ++nn){
        int nt = wid * 2 + nn;
        size_t wi = ((size_t)(kt * 8 + nt) * 64 + lane) * 8;    // Nc/16 = 8
        bf16x8 bh = *(const bf16x8*)(c_W2h + wi);
        bf16x8 bl = *(const bf16x8*)(c_W2l + wi);
        acc2[nn] = __builtin_amdgcn_mfma_f32_16x16x32_bf16(ah, bh, acc2[nn], 0, 0, 0);
        acc2[nn] = __builtin_amdgcn_mfma_f32_16x16x32_bf16(ah, bl, acc2[nn], 0, 0, 0);
        acc2[nn] = __builtin_amdgcn_mfma_f32_16x16x32_bf16(al, bh, acc2[nn], 0, 0, 0);
      }
    }

    float asv[2], adv[2];
#pragma unroll
    for (int nn = 0; nn < 2; ++nn){
      int col = (wid * 2 + nn) * 16 + cl;
      asv[nn] = c_as2f[col]; adv[nn] = c_ad2f[col];
    }
#pragma unroll
    for (int i = 0; i < 4; ++i){
      int row = nb + kgrp * 4 + i;
      float psum = 0.f, pdum = 0.f;
#pragma unroll
      for (int nn = 0; nn < 2; ++nn){
        int col = (wid * 2 + nn) * 16 + cl;
        float v = acc2[nn][i];
        g_h2b[(size_t)row * C_OUT + col] = f2bf(v);
        psum += v * asv[nn]; pdum += v * adv[nn];
      }
      psum += __shfl_xor(psum, 1);  pdum += __shfl_xor(pdum, 1);
      psum += __shfl_xor(psum, 2);  pdum += __shfl_xor(pdum, 2);
      psum += __shfl_xor(psum, 4);  pdum += __shfl_xor(pdum, 4);
      psum += __shfl_xor(psum, 8);  pdum += __shfl_xor(pdum, 8);
      if (cl == 0){ s_ps[wid][kgrp * 4 + i] = psum; s_pd[wid][kgrp * 4 + i] = pdum; }
    }
    __syncthreads();
    if (tidx < 16){
      int r = tidx;
      g_alps2[nb + r] = s_ps[0][r] + s_ps[1][r] + s_ps[2][r] + s_ps[3][r];
      g_alpd2[nb + r] = s_pd[0][r] + s_pd[1][r] + s_pd[2][r] + s_pd[3][r];
    }
  }

  __threadfence();
  cg::this_grid().sync();

  // ---------------- phase 3: agg2 (queue), one wave per node ----------------
  const unsigned int* H1 = (const unsigned int*)g_h2b;
  for (;;){
    __syncthreads();
    if (tidx == 0) s_vb = atomicAdd(&g_q3, 1);
    __syncthreads();
    const int vb = s_vb;
    if (vb >= AGG2_BLKS) break;
    int n = vb * 4 + wid;
    int len = g_cursor[n]; if (len > CAP) len = CAP;
    int i0 = n * CAP, i1 = i0 + len;
    float adn = g_alpd2[n];
    float dpart = 0.f;
    float a0 = 0.f, a1 = 0.f;

    { // implicit self-loop
      float es = g_alps2[n] + adn;
      es = (es > 0.f) ? es : NEG_SLOPE * es;
      float wself = __expf(es);
      if (lane == 0) dpart += wself;
      unsigned int p = H1[(size_t)n * 64 + lane];
      ACC2(p, wself)
    }

    for (int base = i0; base < i1; base += 64){
      int nv = i1 - base; if (nv > 64) nv = 64;
      int sv = 0; float wv = 0.f;
      if (lane < nv){
        sv = g_srcidx[base + lane];
        float e = g_alps2[sv] + adn;
        e = (e > 0.f) ? e : NEG_SLOPE * e;
        wv = __expf(e);
      }
      dpart += wv;
      int j = 0;
      for (; j + 8 <= nv; j += 8){
        int t0 = __shfl(sv, j),     t1 = __shfl(sv, j + 1);
        int t2 = __shfl(sv, j + 2), t3 = __shfl(sv, j + 3);
        int t4 = __shfl(sv, j + 4), t5 = __shfl(sv, j + 5);
        int t6 = __shfl(sv, j + 6), t7 = __shfl(sv, j + 7);
        float w0 = __shfl(wv, j),     w1 = __shfl(wv, j + 1);
        float w2 = __shfl(wv, j + 2), w3 = __shfl(wv, j + 3);
        float w4 = __shfl(wv, j + 4), w5 = __shfl(wv, j + 5);
        float w6 = __shfl(wv, j + 6), w7 = __shfl(wv, j + 7);
        unsigned int p0 = H1[(size_t)t0 * 64 + lane];
        unsigned int p1 = H1[(size_t)t1 * 64 + lane];
        unsigned int p2 = H1[(size_t)t2 * 64 + lane];
        unsigned int p3 = H1[(size_t)t3 * 64 + lane];
        unsigned int p4 = H1[(size_t)t4 * 64 + lane];
        unsigned int p5 = H1[(size_t)t5 * 64 + lane];
        unsigned int p6 = H1[(size_t)t6 * 64 + lane];
        unsigned int p7 = H1[(size_t)t7 * 64 + lane];
        ACC2(p0, w0) ACC2(p1, w1) ACC2(p2, w2) ACC2(p3, w3)
        ACC2(p4, w4) ACC2(p5, w5) ACC2(p6, w6) ACC2(p7, w7)
      }
      for (; j + 4 <= nv; j += 4){
        int t0 = __shfl(sv, j),     t1 = __shfl(sv, j + 1);
        int t2 = __shfl(sv, j + 2), t3 = __shfl(sv, j + 3);
        float w0 = __shfl(wv, j),     w1 = __shfl(wv, j + 1);
        float w2 = __shfl(wv, j + 2), w3 = __shfl(wv, j + 3);
        unsigned int p0 = H1[(size_t)t0 * 64 + lane];
        unsigned int p1 = H1[(size_t)t1 * 64 + lane];
        unsigned int p2 = H1[(size_t)t2 * 64 + lane];
        unsigned int p3 = H1[(size_t)t3 * 64 + lane];
        ACC2(p0, w0) ACC2(p1, w1) ACC2(p2, w2) ACC2(p3, w3)
      }
      for (; j < nv; ++j){
        int t = __shfl(sv, j);
        float w = __shfl(wv, j);
        unsigned int p = H1[(size_t)t * 64 + lane];
        ACC2(p, w)
      }
    }

    float den = dpart;
#pragma unroll
    for (int o = 32; o > 0; o >>= 1) den += __shfl_xor(den, o, 64);
    float inv = 1.f / den;

    float2 o;
    o.x = a0 * inv + c_b2f[2 * lane];
    o.y = a1 * inv + c_b2f[2 * lane + 1];
    ((float2*)OUT)[(size_t)n * 64 + lane] = o;
  }
}

// =======================================================================
// Fallback path: the proven R3 five-kernel pipeline (used only if the
// cooperative launch is unavailable).
// =======================================================================
__device__ __forceinline__ void edge_sd(const int* ei, int e, int& s, int& d){
  if (g_is64){ s = ei[2 * e]; d = ei[2 * (N_EDGES + e)]; }
  else       { s = ei[e];     d = ei[N_EDGES + e]; }
  s = clampi(s); d = clampi(d);
}

__global__ void prep_k(const unsigned int* __restrict__ xw,
                       const int* __restrict__ ei, Ptrs ps){
  __shared__ int s_isf32;
  if (threadIdx.x < 64){
    int lane = (int)threadIdx.x, cnt = 0;
    for (int j = lane; j < 256; j += 64){
      unsigned int e = (xw[j] >> 7) & 0xFFu;
      if (e >= 0x60u && e <= 0x8Fu) ++cnt;
    }
#pragma unroll
    for (int o = 32; o > 0; o >>= 1) cnt += __shfl_xor(cnt, o, 64);
    if (lane == 0) s_isf32 = (cnt < 200) ? 1 : 0;
  }
  __syncthreads();
  const int isf32 = s_isf32;

  if (blockIdx.x == 0 && threadIdx.x < 64){
    unsigned long long anybad = __ballot(ei[2 * (int)threadIdx.x + 1] != 0);
    if (threadIdx.x == 0){ g_isf32 = isf32; g_is64 = (anybad == 0ULL) ? 1 : 0; }
  }

  int tid = (int)(blockIdx.x * blockDim.x + threadIdx.x);
  if (tid < PREP_Z){ g_cursor[tid] = 0; return; }
  int j = tid - PREP_Z;
  auto ld = [&](const void* p, int i) -> float {
    return isf32 ? ((const float*)p)[i] : bf2f(((const unsigned short*)p)[i]);
  };
  if (j < PREP_W1){
    float f = ld(ps.p[0], j);
    int k = j / C_HID, n = j % C_HID;
    int idx = wpack(k, n, C_HID);
    unsigned short h = f2bf(f);
    c_W1h[idx] = h; c_W1l[idx] = f2bf(f - bf2f(h));
    return;
  }
  j -= PREP_W1;
  if (j < PREP_W2){
    float f = ld(ps.p[4], j);
    int k = j / C_OUT, n = j % C_OUT;
    int idx = wpack(k, n, C_OUT);
    unsigned short h = f2bf(f);
    c_W2h[idx] = h; c_W2l[idx] = f2bf(f - bf2f(h));
    return;
  }
  j -= PREP_W2;
  if      (j <  256) c_as1f[j]        = ld(ps.p[1], j);
  else if (j <  512) c_ad1f[j - 256]  = ld(ps.p[2], j - 256);
  else if (j <  768) c_b1f [j - 512]  = ld(ps.p[3], j - 512);
  else if (j <  896) c_as2f[j - 768]  = ld(ps.p[5], j - 768);
  else if (j < 1024) c_ad2f[j - 896]  = ld(ps.p[6], j - 896);
  else if (j < 1152) c_b2f [j - 1024] = ld(ps.p[7], j - 1024);
}

__global__ __launch_bounds__(256) void gemm1_k(const void* __restrict__ xsrc,
                                               const int* __restrict__ ei){
  if (blockIdx.x >= GEMM1_BLKS){
    int e = (int)(blockIdx.x - GEMM1_BLKS) * 256 + (int)threadIdx.x;
    if (e < N_EDGES){
      int s, d;
      edge_sd(ei, e, s, d);
      int pos = atomicAdd(&g_cursor[d], 1);
      if (pos < CAP) g_srcidx[(size_t)d * CAP + pos] = s;
    }
    return;
  }

  __shared__ float s_ps[4][32], s_pd[4][32];
  const bool isf32 = (g_isf32 != 0);
  int wid  = (int)(threadIdx.x >> 6);
  int lane = (int)(threadIdx.x & 63);
  int kgrp = lane >> 4, cl = lane & 15;
  int mbase = blockIdx.x * 32;

  f32x4 acc[2][4];
#pragma unroll
  for (int m = 0; m < 2; ++m)
#pragma unroll
    for (int n = 0; n < 4; ++n) acc[m][n] = (f32x4){0.f, 0.f, 0.f, 0.f};

  for (int kt = 0; kt < 8; ++kt){
    int kbase = kt * 32 + kgrp * 8;
    bf16x8 ah[2], al[2];
    if (isf32){
      const float* Xf = (const float*)xsrc;
#pragma unroll
      for (int m = 0; m < 2; ++m){
        const float4* xp = (const float4*)(Xf + (size_t)(mbase + m * 16 + cl) * 256 + kbase);
        float4 v0 = xp[0], v1 = xp[1];
        float vals[8] = {v0.x, v0.y, v0.z, v0.w, v1.x, v1.y, v1.z, v1.w};
#pragma unroll
        for (int j = 0; j < 8; ++j){
          unsigned short h = f2bf(vals[j]);
          ah[m][j] = (short)h;
          al[m][j] = (short)f2bf(vals[j] - bf2f(h));
        }
      }
    } else {
      const unsigned short* Xb = (const unsigned short*)xsrc;
#pragma unroll
      for (int m = 0; m < 2; ++m){
        ah[m] = *(const bf16x8*)(Xb + (size_t)(mbase + m * 16 + cl) * 256 + kbase);
        al[m] = (bf16x8){0,0,0,0,0,0,0,0};
      }
    }
#pragma unroll
    for (int nn = 0; nn < 4; ++nn){
      int nt = wid * 4 + nn;
      size_t wi = ((size_t)(kt * 16 + nt) * 64 + lane) * 8;
      bf16x8 bh = *(const bf16x8*)(c_W1h + wi);
      bf16x8 bl = *(const bf16x8*)(c_W1l + wi);
#pragma unroll
      for (int m = 0; m < 2; ++m){
        acc[m][nn] = __builtin_amdgcn_mfma_f32_16x16x32_bf16(ah[m], bh, acc[m][nn], 0, 0, 0);
        acc[m][nn] = __builtin_amdgcn_mfma_f32_16x16x32_bf16(ah[m], bl, acc[m][nn], 0, 0, 0);
        acc[m][nn] = __builtin_amdgcn_mfma_f32_16x16x32_bf16(al[m], bh, acc[m][nn], 0, 0, 0);
      }
    }
  }

  float asv[4], adv[4];
#pragma unroll
  for (int nn = 0; nn < 4; ++nn){
    int col = (wid * 4 + nn) * 16 + cl;
    asv[nn] = c_as1f[col]; adv[nn] = c_ad1f[col];
  }
#pragma unroll
  for (int m = 0; m < 2; ++m){
#pragma unroll
    for (int i = 0; i < 4; ++i){
      int rl = m * 16 + kgrp * 4 + i;
      int row = mbase + rl;
      float ps = 0.f, pd = 0.f;
#pragma unroll
      for (int nn = 0; nn < 4; ++nn){
        int col = (wid * 4 + nn) * 16 + cl;
        float v = acc[m][nn][i];
        g_h1b[(size_t)row * C_HID + col] = f2bf(v);
        ps += v * asv[nn]; pd += v * adv[nn];
      }
      ps += __shfl_xor(ps, 1);  pd += __shfl_xor(pd, 1);
      ps += __shfl_xor(ps, 2);  pd += __shfl_xor(pd, 2);
      ps += __shfl_xor(ps, 4);  pd += __shfl_xor(pd, 4);
      ps += __shfl_xor(ps, 8);  pd += __shfl_xor(pd, 8);
      if (cl == 0){ s_ps[wid][rl] = ps; s_pd[wid][rl] = pd; }
    }
  }
  __syncthreads();
  if (threadIdx.x < 32){
    int r = (int)threadIdx.x;
    g_alps1[mbase + r] = s_ps[0][r] + s_ps[1][r] + s_ps[2][r] + s_ps[3][r];
    g_alpd1[mbase + r] = s_pd[0][r] + s_pd[1][r] + s_pd[2][r] + s_pd[3][r];
  }
}

__global__ __launch_bounds__(256) void aggemm_k(){
  __shared__ __align__(16) unsigned short s_hi[16 * AGG_PAD];
  __shared__ __align__(16) unsigned short s_lo[16 * AGG_PAD];
  __shared__ float s_ps[4][16], s_pd[4][16];

  int lane = (int)(threadIdx.x & 63);
  int wid  = (int)(threadIdx.x >> 6);
  int nb   = blockIdx.x * 16;
  const uint2* H2 = (const uint2*)g_h1b;

  for (int q = 0; q < 4; ++q){
    int n = nb + wid * 4 + q;
    int len = g_cursor[n]; if (len > CAP) len = CAP;
    int i0 = n * CAP, i1 = i0 + len;
    float adn = g_alpd1[n];
    float dpart = 0.f;
    float a0 = 0.f, a1 = 0.f, a2 = 0.f, a3 = 0.f;

    {
      float es = g_alps1[n] + adn;
      es = (es > 0.f) ? es : NEG_SLOPE * es;
      float wself = __expf(es);
      if (lane == 0) dpart += wself;
      uint2 p = H2[(size_t)n * 64 + lane];
      ACC4(p, wself)
    }

    for (int base = i0; base < i1; base += 64){
      int nv = i1 - base; if (nv > 64) nv = 64;
      int sv = 0; float wv = 0.f;
      if (lane < nv){
        sv = g_srcidx[base + lane];
        float e = g_alps1[sv] + adn;
        e = (e > 0.f) ? e : NEG_SLOPE * e;
        wv = __expf(e);
      }
      dpart += wv;
      int j = 0;
      for (; j + 8 <= nv; j += 8){
        int s0 = __shfl(sv, j),     s1 = __shfl(sv, j + 1);
        int s2 = __shfl(sv, j + 2), s3 = __shfl(sv, j + 3);
        int s4 = __shfl(sv, j + 4), s5 = __shfl(sv, j + 5);
        int s6 = __shfl(sv, j + 6), s7 = __shfl(sv, j + 7);
        float w0 = __shfl(wv, j),     w1 = __shfl(wv, j + 1);
        float w2 = __shfl(wv, j + 2), w3 = __shfl(wv, j + 3);
        float w4 = __shfl(wv, j + 4), w5 = __shfl(wv, j + 5);
        float w6 = __shfl(wv, j + 6), w7 = __shfl(wv, j + 7);
        uint2 p0 = H2[(size_t)s0 * 64 + lane];
        uint2 p1 = H2[(size_t)s1 * 64 + lane];
        uint2 p2 = H2[(size_t)s2 * 64 + lane];
        uint2 p3 = H2[(size_t)s3 * 64 + lane];
        uint2 p4 = H2[(size_t)s4 * 64 + lane];
        uint2 p5 = H2[(size_t)s5 * 64 + lane];
        uint2 p6 = H2[(size_t)s6 * 64 + lane];
        uint2 p7 = H2[(size_t)s7 * 64 + lane];
        ACC4(p0, w0) ACC4(p1, w1) ACC4(p2, w2) ACC4(p3, w3)
        ACC4(p4, w4) ACC4(p5, w5) ACC4(p6, w6) ACC4(p7, w7)
      }
      for (; j + 4 <= nv; j += 4){
        int s0 = __shfl(sv, j),     s1 = __shfl(sv, j + 1);
        int s2 = __shfl(sv, j + 2), s3 = __shfl(sv, j + 3);
        float w0 = __shfl(wv, j),     w1 = __shfl(wv, j + 1);
        float w2 = __shfl(wv, j + 2), w3 = __shfl(wv, j + 3);
        uint2 p0 = H2[(size_t)s0 * 64 + lane];
        uint2 p1 = H2[(size_t)s1 * 64 + lane];
        uint2 p2 = H2[(size_t)s2 * 64 + lane];
        uint2 p3 = H2[(size_t)s3 * 64 + lane];
        ACC4(p0, w0) ACC4(p1, w1) ACC4(p2, w2) ACC4(p3, w3)
      }
      for (; j < nv; ++j){
        int s = __shfl(sv, j);
        float w = __shfl(wv, j);
        uint2 p = H2[(size_t)s * 64 + lane];
        ACC4(p, w)
      }
    }

    float den = dpart;
#pragma unroll
    for (int o = 32; o > 0; o >>= 1) den += __shfl_xor(den, o, 64);
    float inv = 1.f / den;

    float o0 = a0 * inv + c_b1f[4 * lane];
    float o1 = a1 * inv + c_b1f[4 * lane + 1];
    float o2 = a2 * inv + c_b1f[4 * lane + 2];
    float o3 = a3 * inv + c_b1f[4 * lane + 3];
    o0 = fmaxf(o0, 0.f); o1 = fmaxf(o1, 0.f);
    o2 = fmaxf(o2, 0.f); o3 = fmaxf(o3, 0.f);
    unsigned short h0 = f2bf(o0), h1 = f2bf(o1), h2 = f2bf(o2), h3 = f2bf(o3);
    uint2 ph, pl;
    ph.x = (unsigned)h0 | ((unsigned)h1 << 16);
    ph.y = (unsigned)h2 | ((unsigned)h3 << 16);
    pl.x = (unsigned)f2bf(o0 - bf2f(h0)) | ((unsigned)f2bf(o1 - bf2f(h1)) << 16);
    pl.y = (unsigned)f2bf(o2 - bf2f(h2)) | ((unsigned)f2bf(o3 - bf2f(h3)) << 16);
    int r = wid * 4 + q;
    *(uint2*)&s_hi[r * AGG_PAD + 4 * lane] = ph;
    *(uint2*)&s_lo[r * AGG_PAD + 4 * lane] = pl;
  }
  __syncthreads();

  int kgrp = lane >> 4, cl = lane & 15;
  f32x4 acc[2];
  acc[0] = (f32x4){0.f, 0.f, 0.f, 0.f};
  acc[1] = (f32x4){0.f, 0.f, 0.f, 0.f};
  for (int kt = 0; kt < 8; ++kt){
    int rb = cl * AGG_PAD + kt * 32 + kgrp * 8;
    bf16x8 ah = *(const bf16x8*)&s_hi[rb];
    bf16x8 al = *(const bf16x8*)&s_lo[rb];
#pragma unroll
    for (int nn = 0; nn < 2; ++nn){
      int nt = wid * 2 + nn;
      size_t wi = ((size_t)(kt * 8 + nt) * 64 + lane) * 8;
      bf16x8 bh = *(const bf16x8*)(c_W2h + wi);
      bf16x8 bl = *(const bf16x8*)(c_W2l + wi);
      acc[nn] = __builtin_amdgcn_mfma_f32_16x16x32_bf16(ah, bh, acc[nn], 0, 0, 0);
      acc[nn] = __builtin_amdgcn_mfma_f32_16x16x32_bf16(ah, bl, acc[nn], 0, 0, 0);
      acc[nn] = __builtin_amdgcn_mfma_f32_16x16x32_bf16(al, bh, acc[nn], 0, 0, 0);
    }
  }

  float asv[2], adv[2];
#pragma unroll
  for (int nn = 0; nn < 2; ++nn){
    int col = (wid * 2 + nn) * 16 + cl;
    asv[nn] = c_as2f[col]; adv[nn] = c_ad2f[col];
  }
#pragma unroll
  for (int i = 0; i < 4; ++i){
    int row = nb + kgrp * 4 + i;
    float ps = 0.f, pd = 0.f;
#pragma unroll
    for (int nn = 0; nn < 2; ++nn){
      int col = (wid * 2 + nn) * 16 + cl;
      float v = acc[nn][i];
      g_h2b[(size_t)row * C_OUT + col] = f2bf(v);
      ps += v * asv[nn]; pd += v * adv[nn];
    }
    ps += __shfl_xor(ps, 1);  pd += __shfl_xor(pd, 1);
    ps += __shfl_xor(ps, 2);  pd += __shfl_xor(pd, 2);
    ps += __shfl_xor(ps, 4);  pd += __shfl_xor(pd, 4);
    ps += __shfl_xor(ps, 8);  pd += __shfl_xor(pd, 8);
    if (cl == 0){ s_ps[wid][kgrp * 4 + i] = ps; s_pd[wid][kgrp * 4 + i] = pd; }
  }
  __syncthreads();
  if (threadIdx.x < 16){
    int r = (int)threadIdx.x;
    g_alps2[nb + r] = s_ps[0][r] + s_ps[1][r] + s_ps[2][r] + s_ps[3][r];
    g_alpd2[nb + r] = s_pd[0][r] + s_pd[1][r] + s_pd[2][r] + s_pd[3][r];
  }
}

__global__ __launch_bounds__(256) void agg2_k(float* OUT){
  int lane = (int)(threadIdx.x & 63);
  int n = blockIdx.x * 4 + (int)(threadIdx.x >> 6);
  int len = g_cursor[n]; if (len > CAP) len = CAP;
  int i0 = n * CAP, i1 = i0 + len;
  float adn = g_alpd2[n];
  float dpart = 0.f;
  float a0 = 0.f, a1 = 0.f;
  const unsigned int* H1 = (const unsigned int*)g_h2b;

  {
    float es = g_alps2[n] + adn;
    es = (es > 0.f) ? es : NEG_SLOPE * es;
    float wself = __expf(es);
    if (lane == 0) dpart += wself;
    unsigned int p = H1[(size_t)n * 64 + lane];
    ACC2(p, wself)
  }

  for (int base = i0; base < i1; base += 64){
    int nv = i1 - base; if (nv > 64) nv = 64;
    int sv = 0; float wv = 0.f;
    if (lane < nv){
      sv = g_srcidx[base + lane];
      float e = g_alps2[sv] + adn;
      e = (e > 0.f) ? e : NEG_SLOPE * e;
      wv = __expf(e);
    }
    dpart += wv;
    int j = 0;
    for (; j + 8 <= nv; j += 8){
      int s0 = __shfl(sv, j),     s1 = __shfl(sv, j + 1);
      int s2 = __shfl(sv, j + 2), s3 = __shfl(sv, j + 3);
      int s4 = __shfl(sv, j + 4), s5 = __shfl(sv, j + 5);
      int s6 = __shfl(sv, j + 6), s7 = __shfl(sv, j + 7);
      float w0 = __shfl(wv, j),     w1 = __shfl(wv, j + 1);
      float w2 = __shfl(wv, j + 2), w3 = __shfl(wv, j + 3);
      float w4 = __shfl(wv, j + 4), w5 = __shfl(wv, j + 5);
      float w6 = __shfl(wv, j + 6), w7 = __shfl(wv, j + 7);
      unsigned int p0 = H1[(size_t)s0 * 64 + lane];
      unsigned int p1 = H1[(size_t)s1 * 64 + lane];
      unsigned int p2 = H1[(size_t)s2 * 64 + lane];
      unsigned int p3 = H1[(size_t)s3 * 64 + lane];
      unsigned int p4 = H1[(size_t)s4 * 64 + lane];
      unsigned int p5 = H1[(size_t)s5 * 64 + lane];
      unsigned int p6 = H1[(size_t)s6 * 64 + lane];
      unsigned int p7 = H1[(size_t)s7 * 64 + lane];
      ACC2(p0, w0) ACC2(p1, w1) ACC2(p2, w2) ACC2(p3, w3)
      ACC2(p4, w4) ACC2(p5, w5) ACC2(p6, w6) ACC2(p7, w7)
    }
    for (; j + 4 <= nv; j += 4){
      int s0 = __shfl(sv, j),     s1 = __shfl(sv, j + 1);
      int s2 = __shfl(sv, j + 2), s3 = __shfl(sv, j + 3);
      float w0 = __shfl(wv, j),     w1 = __shfl(wv, j + 1);
      float w2 = __shfl(wv, j + 2), w3 = __shfl(wv, j + 3);
      unsigned int p0 = H1[(size_t)s0 * 64 + lane];
      unsigned int p1 = H1[(size_t)s1 * 64 + lane];
      unsigned int p2 = H1[(size_t)s2 * 64 + lane];
      unsigned int p3 = H1[(size_t)s3 * 64 + lane];
      ACC2(p0, w0) ACC2(p1, w1) ACC2(p2, w2) ACC2(p3, w3)
    }
    for (; j < nv; ++j){
      int s = __shfl(sv, j);
      float w = __shfl(wv, j);
      unsigned int p = H1[(size_t)s * 64 + lane];
      ACC2(p, w)
    }
  }

  float den = dpart;
#pragma unroll
  for (int o = 32; o > 0; o >>= 1) den += __shfl_xor(den, o, 64);
  float inv = 1.f / den;

  float2 o;
  o.x = a0 * inv + c_b2f[2 * lane];
  o.y = a1 * inv + c_b2f[2 * lane + 1];
  ((float2*)OUT)[(size_t)n * 64 + lane] = o;
}

extern "C" void kernel_launch(void* const* d_in, const int* in_sizes, int n_in,
                              void* d_out, int out_size, void* d_ws, size_t ws_size,
                              hipStream_t stream){
  (void)in_sizes; (void)n_in; (void)out_size; (void)d_ws; (void)ws_size;
  const void* x  = d_in[0];
  const int*  ei = (const int*)d_in[1];
  float* out = (float*)d_out;

  Ptrs ps;
  ps.p[0] = d_in[2]; ps.p[1] = d_in[3]; ps.p[2] = d_in[4]; ps.p[3] = d_in[5];
  ps.p[4] = d_in[6]; ps.p[5] = d_in[7]; ps.p[6] = d_in[8]; ps.p[7] = d_in[9];

  // ---- cooperative mega-kernel path ----
  static int coop_grid = -1;
  if (coop_grid < 0){
    int nb = 0;
    if (hipOccupancyMaxActiveBlocksPerMultiprocessor(&nb, fused_k, 256, 0) != hipSuccess) nb = 0;
    int g = nb * 256;              // 256 CUs on MI355X
    if (g > 2048) g = 2048;        // queues handle any size; cap for sanity
    coop_grid = (nb > 0) ? g : 0;
  }
  if (coop_grid > 0){
    const unsigned int* xw = (const unsigned int*)x;
    void* args[4] = { (void*)&xw, (void*)&ei, (void*)&out, (void*)&ps };
    hipError_t err = hipLaunchCooperativeKernel((const void*)fused_k,
                                                dim3((unsigned)coop_grid), dim3(256),
                                                args, 0, stream);
    if (err == hipSuccess) return;
    coop_grid = 0;                 // cooperative unsupported: fall back permanently
  }

  // ---- fallback: proven R3 five-kernel pipeline ----
  prep_k<<<(PREP_T + 255) / 256, 256, 0, stream>>>((const unsigned int*)x, ei, ps);
  gemm1_k<<<GEMM1_BLKS + SCAT_BLKS, 256, 0, stream>>>(x, ei);
  aggemm_k<<<AGGEMM_BLKS, 256, 0, stream>>>();
  agg2_k<<<AGG2_BLKS, 256, 0, stream>>>(out);
}

// Round 5
// 489.482 us; speedup vs baseline: 1.2709x; 1.2709x over previous
//
#include <hip/hip_runtime.h>
#include <hip/hip_cooperative_groups.h>
#include <math.h>

namespace cg = cooperative_groups;

#define N_NODES 20000
#define N_EDGES 320000
#define C_IN  256
#define C_HID 256
#define C_OUT 128
#define NEG_SLOPE 0.2f
#define CAP   256   // padded-CSR slots per node (real edges only; self-loop implicit)
#define GEMM1_BLKS (N_NODES / 32)          // 625
#define SCAT_BLKS  ((N_EDGES + 255) / 256) // 1250
#define AGGEMM_BLKS (N_NODES / 16)         // 1250
#define AGG2_BLKS  (N_NODES / 4)           // 5000
#define AGG_PAD 280 // 256 + 24: LDS row stride (560 B = 16B-aligned, 8 bank-start groups)

typedef __attribute__((ext_vector_type(8))) short bf16x8;
typedef __attribute__((ext_vector_type(4))) float f32x4;

// ---- all scratch in module globals (ws_size unknown; globals are safe) ----
__device__ __align__(16) unsigned short c_W1h[C_IN * C_HID], c_W1l[C_IN * C_HID];
__device__ __align__(16) unsigned short c_W2h[C_HID * C_OUT], c_W2l[C_HID * C_OUT];
__device__ float c_as1f[C_HID], c_ad1f[C_HID], c_b1f[C_HID];
__device__ float c_as2f[C_OUT], c_ad2f[C_OUT], c_b2f[C_OUT];
__device__ __align__(16) unsigned short g_h1b[(size_t)N_NODES * C_HID]; // h1 bf16
__device__ __align__(16) unsigned short g_h2b[(size_t)N_NODES * C_OUT]; // h2 bf16
__device__ float g_alps1[N_NODES], g_alpd1[N_NODES];
__device__ float g_alps2[N_NODES], g_alpd2[N_NODES];
__device__ int   g_cursor[N_NODES];            // per-node real-edge count
__device__ int   g_srcidx[(size_t)N_NODES * CAP];
__device__ int   g_is64;    // edge_index arrived as raw int64 words (fallback path)
__device__ int   g_isf32;   // float inputs arrived as raw fp32 words (fallback path)
__device__ int   g_q1, g_q2, g_q3;  // dynamic virtual-block queues (coop kernel)

__device__ __forceinline__ float bf2f(unsigned short b){
  unsigned int u = ((unsigned int)b) << 16;
  return __builtin_bit_cast(float, u);
}
__device__ __forceinline__ unsigned short f2bf(float f){
  unsigned int u = __builtin_bit_cast(unsigned int, f);
  u += 0x7fffu + ((u >> 16) & 1u);   // round-to-nearest-even
  return (unsigned short)(u >> 16);
}
__device__ __forceinline__ int clampi(int v){
  v = v < 0 ? 0 : v;
  return v >= N_NODES ? N_NODES - 1 : v;
}

struct Ptrs { const void* p[8]; };

// pack (k, n) of a [K][Nc] weight into MFMA B-fragment order
__device__ __forceinline__ int wpack(int k, int n, int Nc){
  return (((k >> 5) * (Nc / 16) + (n >> 4)) * 64 + (((k >> 3) & 3) * 16 + (n & 15))) * 8 + (k & 7);
}

#define PREP_Z  N_NODES
#define PREP_W1 (C_IN * C_HID)
#define PREP_W2 (C_HID * C_OUT)
#define PREP_T  (PREP_Z + PREP_W1 + PREP_W2 + 2 * C_HID + C_HID + 2 * C_OUT + C_OUT)

#define ACC4(p, ww) { \
  a0 += (ww) * bf2f((unsigned short)((p).x & 0xFFFFu)); \
  a1 += (ww) * bf2f((unsigned short)((p).x >> 16)); \
  a2 += (ww) * bf2f((unsigned short)((p).y & 0xFFFFu)); \
  a3 += (ww) * bf2f((unsigned short)((p).y >> 16)); }

#define ACC2(p, ww) { \
  a0 += (ww) * bf2f((unsigned short)((p) & 0xFFFFu)); \
  a1 += (ww) * bf2f((unsigned short)((p) >> 16)); }

// =======================================================================
// fused_k: ALL FIVE PHASES in one cooperative dispatch.
//   P0 prep (probe + cursor zero + weight pack)  -> grid.sync
//   P1 gemm1 tiles + edge scatter (dynamic queue) -> grid.sync
//   P2 agg1+gemm2 fused tiles (dynamic queue)     -> grid.sync
//   P3 agg2 (dynamic queue)
// R4 lesson: grid MUST be strictly co-resident. The occupancy API ignores
// the MFMA accumulator (AGPR) footprint on gfx950's unified file and
// over-reports 2x (R4: promised 8/CU, OccupancyPercent showed ~4/CU ->
// CWSR time-slicing, 850us of idle spin). Launch (nb/2 - 1) blocks/CU.
// =======================================================================
__global__ __launch_bounds__(256, 4) void fused_k(const unsigned int* __restrict__ xw,
                                                  const int* __restrict__ ei,
                                                  float* __restrict__ OUT,
                                                  Ptrs ps){
  __shared__ __align__(16) unsigned short s_hi[16 * AGG_PAD];
  __shared__ __align__(16) unsigned short s_lo[16 * AGG_PAD];
  __shared__ float s_ps[4][32], s_pd[4][32];
  __shared__ int s_flags, s_vb;

  const int tidx = (int)threadIdx.x;
  const int lane = tidx & 63;
  const int wid  = tidx >> 6;

  // ---------------- phase 0: probe + cursor zero + weight pack ----------------
  if (tidx < 64){
    int cnt = 0;
    for (int j = lane; j < 256; j += 64){
      unsigned int e = (xw[j] >> 7) & 0xFFu;
      if (e >= 0x60u && e <= 0x8Fu) ++cnt;
    }
#pragma unroll
    for (int o = 32; o > 0; o >>= 1) cnt += __shfl_xor(cnt, o, 64);
    unsigned long long anybad = __ballot(ei[2 * lane + 1] != 0);
    if (lane == 0) s_flags = ((cnt < 200) ? 1 : 0) | ((anybad == 0ULL) ? 2 : 0);
  }
  if (blockIdx.x == 0 && tidx == 0){ g_q1 = 0; g_q2 = 0; g_q3 = 0; }
  __syncthreads();
  const bool isf32 = (s_flags & 1) != 0;
  const bool is64  = (s_flags & 2) != 0;

  const int total = (int)(gridDim.x * blockDim.x);
  auto ld = [&](const void* p, int i) -> float {
    return isf32 ? ((const float*)p)[i] : bf2f(((const unsigned short*)p)[i]);
  };
  for (int t = (int)(blockIdx.x * blockDim.x) + tidx; t < PREP_T; t += total){
    if (t < PREP_Z){ g_cursor[t] = 0; continue; }
    int j = t - PREP_Z;
    if (j < PREP_W1){
      float f = ld(ps.p[0], j);
      int k = j / C_HID, n = j % C_HID;
      int idx = wpack(k, n, C_HID);
      unsigned short h = f2bf(f);
      c_W1h[idx] = h; c_W1l[idx] = f2bf(f - bf2f(h));
      continue;
    }
    j -= PREP_W1;
    if (j < PREP_W2){
      float f = ld(ps.p[4], j);
      int k = j / C_OUT, n = j % C_OUT;
      int idx = wpack(k, n, C_OUT);
      unsigned short h = f2bf(f);
      c_W2h[idx] = h; c_W2l[idx] = f2bf(f - bf2f(h));
      continue;
    }
    j -= PREP_W2;
    if      (j <  256) c_as1f[j]        = ld(ps.p[1], j);
    else if (j <  512) c_ad1f[j - 256]  = ld(ps.p[2], j - 256);
    else if (j <  768) c_b1f [j - 512]  = ld(ps.p[3], j - 512);
    else if (j <  896) c_as2f[j - 768]  = ld(ps.p[5], j - 768);
    else if (j < 1024) c_ad2f[j - 896]  = ld(ps.p[6], j - 896);
    else if (j < 1152) c_b2f [j - 1024] = ld(ps.p[7], j - 1024);
  }

  __threadfence();
  cg::this_grid().sync();

  // ---------------- phase 1: gemm1 tiles + edge scatter (queue) ----------------
  for (;;){
    __syncthreads();                       // protects s_vb / s_ps from prev iter
    if (tidx == 0) s_vb = atomicAdd(&g_q1, 1);
    __syncthreads();
    const int vb = s_vb;
    if (vb >= GEMM1_BLKS + SCAT_BLKS) break;

    if (vb >= GEMM1_BLKS){                 // ---- scatter chunk ----
      int e = (vb - GEMM1_BLKS) * 256 + tidx;
      if (e < N_EDGES){
        int s, d;
        if (is64){ s = ei[2 * e]; d = ei[2 * (N_EDGES + e)]; }
        else     { s = ei[e];     d = ei[N_EDGES + e]; }
        s = clampi(s); d = clampi(d);
        int pos = atomicAdd(&g_cursor[d], 1);
        if (pos < CAP) g_srcidx[(size_t)d * CAP + pos] = s;
      }
      continue;
    }

    // ---- gemm1 tile: rows [vb*32, vb*32+32), all 256 cols ----
    int kgrp = lane >> 4, cl = lane & 15;
    int mbase = vb * 32;
    f32x4 acc[2][4];
#pragma unroll
    for (int m = 0; m < 2; ++m)
#pragma unroll
      for (int n = 0; n < 4; ++n) acc[m][n] = (f32x4){0.f, 0.f, 0.f, 0.f};

    for (int kt = 0; kt < 8; ++kt){
      int kbase = kt * 32 + kgrp * 8;
      bf16x8 ah[2], al[2];
      if (isf32){
        const float* Xf = (const float*)xw;
#pragma unroll
        for (int m = 0; m < 2; ++m){
          const float4* xp = (const float4*)(Xf + (size_t)(mbase + m * 16 + cl) * 256 + kbase);
          float4 v0 = xp[0], v1 = xp[1];
          float vals[8] = {v0.x, v0.y, v0.z, v0.w, v1.x, v1.y, v1.z, v1.w};
#pragma unroll
          for (int j = 0; j < 8; ++j){
            unsigned short h = f2bf(vals[j]);
            ah[m][j] = (short)h;
            al[m][j] = (short)f2bf(vals[j] - bf2f(h));
          }
        }
      } else {
        const unsigned short* Xb = (const unsigned short*)xw;
#pragma unroll
        for (int m = 0; m < 2; ++m){
          ah[m] = *(const bf16x8*)(Xb + (size_t)(mbase + m * 16 + cl) * 256 + kbase);
          al[m] = (bf16x8){0,0,0,0,0,0,0,0};
        }
      }
#pragma unroll
      for (int nn = 0; nn < 4; ++nn){
        int nt = wid * 4 + nn;
        size_t wi = ((size_t)(kt * 16 + nt) * 64 + lane) * 8;   // Nc/16 = 16
        bf16x8 bh = *(const bf16x8*)(c_W1h + wi);
        bf16x8 bl = *(const bf16x8*)(c_W1l + wi);
#pragma unroll
        for (int m = 0; m < 2; ++m){
          acc[m][nn] = __builtin_amdgcn_mfma_f32_16x16x32_bf16(ah[m], bh, acc[m][nn], 0, 0, 0);
          acc[m][nn] = __builtin_amdgcn_mfma_f32_16x16x32_bf16(ah[m], bl, acc[m][nn], 0, 0, 0);
          acc[m][nn] = __builtin_amdgcn_mfma_f32_16x16x32_bf16(al[m], bh, acc[m][nn], 0, 0, 0);
        }
      }
    }

    float asv[4], adv[4];
#pragma unroll
    for (int nn = 0; nn < 4; ++nn){
      int col = (wid * 4 + nn) * 16 + cl;
      asv[nn] = c_as1f[col]; adv[nn] = c_ad1f[col];
    }
#pragma unroll
    for (int m = 0; m < 2; ++m){
#pragma unroll
      for (int i = 0; i < 4; ++i){
        int rl = m * 16 + kgrp * 4 + i;
        int row = mbase + rl;
        float psum = 0.f, pdum = 0.f;
#pragma unroll
        for (int nn = 0; nn < 4; ++nn){
          int col = (wid * 4 + nn) * 16 + cl;
          float v = acc[m][nn][i];
          g_h1b[(size_t)row * C_HID + col] = f2bf(v);
          psum += v * asv[nn]; pdum += v * adv[nn];
        }
        psum += __shfl_xor(psum, 1);  pdum += __shfl_xor(pdum, 1);
        psum += __shfl_xor(psum, 2);  pdum += __shfl_xor(pdum, 2);
        psum += __shfl_xor(psum, 4);  pdum += __shfl_xor(pdum, 4);
        psum += __shfl_xor(psum, 8);  pdum += __shfl_xor(pdum, 8);
        if (cl == 0){ s_ps[wid][rl] = psum; s_pd[wid][rl] = pdum; }
      }
    }
    __syncthreads();
    if (tidx < 32){
      int r = tidx;
      g_alps1[mbase + r] = s_ps[0][r] + s_ps[1][r] + s_ps[2][r] + s_ps[3][r];
      g_alpd1[mbase + r] = s_pd[0][r] + s_pd[1][r] + s_pd[2][r] + s_pd[3][r];
    }
  }

  __threadfence();
  cg::this_grid().sync();

  // ---------------- phase 2: agg1 + gemm2 fused tiles (queue) ----------------
  for (;;){
    __syncthreads();                       // protects s_vb / s_hi / s_ps
    if (tidx == 0) s_vb = atomicAdd(&g_q2, 1);
    __syncthreads();
    const int vb = s_vb;
    if (vb >= AGGEMM_BLKS) break;
    const int nb = vb * 16;
    const uint2* H2 = (const uint2*)g_h1b;

    // ---- agg: each wave aggregates 4 nodes ----
    for (int q = 0; q < 4; ++q){
      int n = nb + wid * 4 + q;
      int len = g_cursor[n]; if (len > CAP) len = CAP;
      int i0 = n * CAP, i1 = i0 + len;
      float adn = g_alpd1[n];
      float dpart = 0.f;
      float a0 = 0.f, a1 = 0.f, a2 = 0.f, a3 = 0.f;

      { // implicit self-loop
        float es = g_alps1[n] + adn;
        es = (es > 0.f) ? es : NEG_SLOPE * es;
        float wself = __expf(es);
        if (lane == 0) dpart += wself;
        uint2 p = H2[(size_t)n * 64 + lane];
        ACC4(p, wself)
      }

      for (int base = i0; base < i1; base += 64){
        int nv = i1 - base; if (nv > 64) nv = 64;
        int sv = 0; float wv = 0.f;
        if (lane < nv){
          sv = g_srcidx[base + lane];
          float e = g_alps1[sv] + adn;
          e = (e > 0.f) ? e : NEG_SLOPE * e;
          wv = __expf(e);
        }
        dpart += wv;
        int j = 0;
        for (; j + 8 <= nv; j += 8){
          int t0 = __shfl(sv, j),     t1 = __shfl(sv, j + 1);
          int t2 = __shfl(sv, j + 2), t3 = __shfl(sv, j + 3);
          int t4 = __shfl(sv, j + 4), t5 = __shfl(sv, j + 5);
          int t6 = __shfl(sv, j + 6), t7 = __shfl(sv, j + 7);
          float w0 = __shfl(wv, j),     w1 = __shfl(wv, j + 1);
          float w2 = __shfl(wv, j + 2), w3 = __shfl(wv, j + 3);
          float w4 = __shfl(wv, j + 4), w5 = __shfl(wv, j + 5);
          float w6 = __shfl(wv, j + 6), w7 = __shfl(wv, j + 7);
          uint2 p0 = H2[(size_t)t0 * 64 + lane];
          uint2 p1 = H2[(size_t)t1 * 64 + lane];
          uint2 p2 = H2[(size_t)t2 * 64 + lane];
          uint2 p3 = H2[(size_t)t3 * 64 + lane];
          uint2 p4 = H2[(size_t)t4 * 64 + lane];
          uint2 p5 = H2[(size_t)t5 * 64 + lane];
          uint2 p6 = H2[(size_t)t6 * 64 + lane];
          uint2 p7 = H2[(size_t)t7 * 64 + lane];
          ACC4(p0, w0) ACC4(p1, w1) ACC4(p2, w2) ACC4(p3, w3)
          ACC4(p4, w4) ACC4(p5, w5) ACC4(p6, w6) ACC4(p7, w7)
        }
        for (; j + 4 <= nv; j += 4){
          int t0 = __shfl(sv, j),     t1 = __shfl(sv, j + 1);
          int t2 = __shfl(sv, j + 2), t3 = __shfl(sv, j + 3);
          float w0 = __shfl(wv, j),     w1 = __shfl(wv, j + 1);
          float w2 = __shfl(wv, j + 2), w3 = __shfl(wv, j + 3);
          uint2 p0 = H2[(size_t)t0 * 64 + lane];
          uint2 p1 = H2[(size_t)t1 * 64 + lane];
          uint2 p2 = H2[(size_t)t2 * 64 + lane];
          uint2 p3 = H2[(size_t)t3 * 64 + lane];
          ACC4(p0, w0) ACC4(p1, w1) ACC4(p2, w2) ACC4(p3, w3)
        }
        for (; j < nv; ++j){
          int t = __shfl(sv, j);
          float w = __shfl(wv, j);
          uint2 p = H2[(size_t)t * 64 + lane];
          ACC4(p, w)
        }
      }

      float den = dpart;
#pragma unroll
      for (int o = 32; o > 0; o >>= 1) den += __shfl_xor(den, o, 64);
      float inv = 1.f / den;

      float o0 = a0 * inv + c_b1f[4 * lane];
      float o1 = a1 * inv + c_b1f[4 * lane + 1];
      float o2 = a2 * inv + c_b1f[4 * lane + 2];
      float o3 = a3 * inv + c_b1f[4 * lane + 3];
      o0 = fmaxf(o0, 0.f); o1 = fmaxf(o1, 0.f);
      o2 = fmaxf(o2, 0.f); o3 = fmaxf(o3, 0.f);
      unsigned short h0 = f2bf(o0), h1 = f2bf(o1), h2 = f2bf(o2), h3 = f2bf(o3);
      uint2 ph, pl;
      ph.x = (unsigned)h0 | ((unsigned)h1 << 16);
      ph.y = (unsigned)h2 | ((unsigned)h3 << 16);
      pl.x = (unsigned)f2bf(o0 - bf2f(h0)) | ((unsigned)f2bf(o1 - bf2f(h1)) << 16);
      pl.y = (unsigned)f2bf(o2 - bf2f(h2)) | ((unsigned)f2bf(o3 - bf2f(h3)) << 16);
      int r = wid * 4 + q;
      *(uint2*)&s_hi[r * AGG_PAD + 4 * lane] = ph;
      *(uint2*)&s_lo[r * AGG_PAD + 4 * lane] = pl;
    }
    __syncthreads();

    // ---- gemm2 tile: rows [nb, nb+16), cols [0,128), K=256 ----
    int kgrp = lane >> 4, cl = lane & 15;
    f32x4 acc2[2];
    acc2[0] = (f32x4){0.f, 0.f, 0.f, 0.f};
    acc2[1] = (f32x4){0.f, 0.f, 0.f, 0.f};
    for (int kt = 0; kt < 8; ++kt){
      int rb = cl * AGG_PAD + kt * 32 + kgrp * 8;
      bf16x8 ah = *(const bf16x8*)&s_hi[rb];
      bf16x8 al = *(const bf16x8*)&s_lo[rb];
#pragma unroll
      for (int nn = 0; nn < 2; ++nn){
        int nt = wid * 2 + nn;
        size_t wi = ((size_t)(kt * 8 + nt) * 64 + lane) * 8;    // Nc/16 = 8
        bf16x8 bh = *(const bf16x8*)(c_W2h + wi);
        bf16x8 bl = *(const bf16x8*)(c_W2l + wi);
        acc2[nn] = __builtin_amdgcn_mfma_f32_16x16x32_bf16(ah, bh, acc2[nn], 0, 0, 0);
        acc2[nn] = __builtin_amdgcn_mfma_f32_16x16x32_bf16(ah, bl, acc2[nn], 0, 0, 0);
        acc2[nn] = __builtin_amdgcn_mfma_f32_16x16x32_bf16(al, bh, acc2[nn], 0, 0, 0);
      }
    }

    float asv[2], adv[2];
#pragma unroll
    for (int nn = 0; nn < 2; ++nn){
      int col = (wid * 2 + nn) * 16 + cl;
      asv[nn] = c_as2f[col]; adv[nn] = c_ad2f[col];
    }
#pragma unroll
    for (int i = 0; i < 4; ++i){
      int row = nb + kgrp * 4 + i;
      float psum = 0.f, pdum = 0.f;
#pragma unroll
      for (int nn = 0; nn < 2; ++nn){
        int col = (wid * 2 + nn) * 16 + cl;
        float v = acc2[nn][i];
        g_h2b[(size_t)row * C_OUT + col] = f2bf(v);
        psum += v * asv[nn]; pdum += v * adv[nn];
      }
      psum += __shfl_xor(psum, 1);  pdum += __shfl_xor(pdum, 1);
      psum += __shfl_xor(psum, 2);  pdum += __shfl_xor(pdum, 2);
      psum += __shfl_xor(psum, 4);  pdum += __shfl_xor(pdum, 4);
      psum += __shfl_xor(psum, 8);  pdum += __shfl_xor(pdum, 8);
      if (cl == 0){ s_ps[wid][kgrp * 4 + i] = psum; s_pd[wid][kgrp * 4 + i] = pdum; }
    }
    __syncthreads();
    if (tidx < 16){
      int r = tidx;
      g_alps2[nb + r] = s_ps[0][r] + s_ps[1][r] + s_ps[2][r] + s_ps[3][r];
      g_alpd2[nb + r] = s_pd[0][r] + s_pd[1][r] + s_pd[2][r] + s_pd[3][r];
    }
  }

  __threadfence();
  cg::this_grid().sync();

  // ---------------- phase 3: agg2 (queue), one wave per node ----------------
  const unsigned int* H1 = (const unsigned int*)g_h2b;
  for (;;){
    __syncthreads();
    if (tidx == 0) s_vb = atomicAdd(&g_q3, 1);
    __syncthreads();
    const int vb = s_vb;
    if (vb >= AGG2_BLKS) break;
    int n = vb * 4 + wid;
    int len = g_cursor[n]; if (len > CAP) len = CAP;
    int i0 = n * CAP, i1 = i0 + len;
    float adn = g_alpd2[n];
    float dpart = 0.f;
    float a0 = 0.f, a1 = 0.f;

    { // implicit self-loop
      float es = g_alps2[n] + adn;
      es = (es > 0.f) ? es : NEG_SLOPE * es;
      float wself = __expf(es);
      if (lane == 0) dpart += wself;
      unsigned int p = H1[(size_t)n * 64 + lane];
      ACC2(p, wself)
    }

    for (int base = i0; base < i1; base += 64){
      int nv = i1 - base; if (nv > 64) nv = 64;
      int sv = 0; float wv = 0.f;
      if (lane < nv){
        sv = g_srcidx[base + lane];
        float e = g_alps2[sv] + adn;
        e = (e > 0.f) ? e : NEG_SLOPE * e;
        wv = __expf(e);
      }
      dpart += wv;
      int j = 0;
      for (; j + 8 <= nv; j += 8){
        int t0 = __shfl(sv, j),     t1 = __shfl(sv, j + 1);
        int t2 = __shfl(sv, j + 2), t3 = __shfl(sv, j + 3);
        int t4 = __shfl(sv, j + 4), t5 = __shfl(sv, j + 5);
        int t6 = __shfl(sv, j + 6), t7 = __shfl(sv, j + 7);
        float w0 = __shfl(wv, j),     w1 = __shfl(wv, j + 1);
        float w2 = __shfl(wv, j + 2), w3 = __shfl(wv, j + 3);
        float w4 = __shfl(wv, j + 4), w5 = __shfl(wv, j + 5);
        float w6 = __shfl(wv, j + 6), w7 = __shfl(wv, j + 7);
        unsigned int p0 = H1[(size_t)t0 * 64 + lane];
        unsigned int p1 = H1[(size_t)t1 * 64 + lane];
        unsigned int p2 = H1[(size_t)t2 * 64 + lane];
        unsigned int p3 = H1[(size_t)t3 * 64 + lane];
        unsigned int p4 = H1[(size_t)t4 * 64 + lane];
        unsigned int p5 = H1[(size_t)t5 * 64 + lane];
        unsigned int p6 = H1[(size_t)t6 * 64 + lane];
        unsigned int p7 = H1[(size_t)t7 * 64 + lane];
        ACC2(p0, w0) ACC2(p1, w1) ACC2(p2, w2) ACC2(p3, w3)
        ACC2(p4, w4) ACC2(p5, w5) ACC2(p6, w6) ACC2(p7, w7)
      }
      for (; j + 4 <= nv; j += 4){
        int t0 = __shfl(sv, j),     t1 = __shfl(sv, j + 1);
        int t2 = __shfl(sv, j + 2), t3 = __shfl(sv, j + 3);
        float w0 = __shfl(wv, j),     w1 = __shfl(wv, j + 1);
        float w2 = __shfl(wv, j + 2), w3 = __shfl(wv, j + 3);
        unsigned int p0 = H1[(size_t)t0 * 64 + lane];
        unsigned int p1 = H1[(size_t)t1 * 64 + lane];
        unsigned int p2 = H1[(size_t)t2 * 64 + lane];
        unsigned int p3 = H1[(size_t)t3 * 64 + lane];
        ACC2(p0, w0) ACC2(p1, w1) ACC2(p2, w2) ACC2(p3, w3)
      }
      for (; j < nv; ++j){
        int t = __shfl(sv, j);
        float w = __shfl(wv, j);
        unsigned int p = H1[(size_t)t * 64 + lane];
        ACC2(p, w)
      }
    }

    float den = dpart;
#pragma unroll
    for (int o = 32; o > 0; o >>= 1) den += __shfl_xor(den, o, 64);
    float inv = 1.f / den;

    float2 o;
    o.x = a0 * inv + c_b2f[2 * lane];
    o.y = a1 * inv + c_b2f[2 * lane + 1];
    ((float2*)OUT)[(size_t)n * 64 + lane] = o;
  }
}

// =======================================================================
// Fallback path: the proven R3 five-kernel pipeline (used only if the
// cooperative launch is unavailable).
// =======================================================================
__device__ __forceinline__ void edge_sd(const int* ei, int e, int& s, int& d){
  if (g_is64){ s = ei[2 * e]; d = ei[2 * (N_EDGES + e)]; }
  else       { s = ei[e];     d = ei[N_EDGES + e]; }
  s = clampi(s); d = clampi(d);
}

__global__ void prep_k(const unsigned int* __restrict__ xw,
                       const int* __restrict__ ei, Ptrs ps){
  __shared__ int s_isf32;
  if (threadIdx.x < 64){
    int lane = (int)threadIdx.x, cnt = 0;
    for (int j = lane; j < 256; j += 64){
      unsigned int e = (xw[j] >> 7) & 0xFFu;
      if (e >= 0x60u && e <= 0x8Fu) ++cnt;
    }
#pragma unroll
    for (int o = 32; o > 0; o >>= 1) cnt += __shfl_xor(cnt, o, 64);
    if (lane == 0) s_isf32 = (cnt < 200) ? 1 : 0;
  }
  __syncthreads();
  const int isf32 = s_isf32;

  if (blockIdx.x == 0 && threadIdx.x < 64){
    unsigned long long anybad = __ballot(ei[2 * (int)threadIdx.x + 1] != 0);
    if (threadIdx.x == 0){ g_isf32 = isf32; g_is64 = (anybad == 0ULL) ? 1 : 0; }
  }

  int tid = (int)(blockIdx.x * blockDim.x + threadIdx.x);
  if (tid < PREP_Z){ g_cursor[tid] = 0; return; }
  int j = tid - PREP_Z;
  auto ld = [&](const void* p, int i) -> float {
    return isf32 ? ((const float*)p)[i] : bf2f(((const unsigned short*)p)[i]);
  };
  if (j < PREP_W1){
    float f = ld(ps.p[0], j);
    int k = j / C_HID, n = j % C_HID;
    int idx = wpack(k, n, C_HID);
    unsigned short h = f2bf(f);
    c_W1h[idx] = h; c_W1l[idx] = f2bf(f - bf2f(h));
    return;
  }
  j -= PREP_W1;
  if (j < PREP_W2){
    float f = ld(ps.p[4], j);
    int k = j / C_OUT, n = j % C_OUT;
    int idx = wpack(k, n, C_OUT);
    unsigned short h = f2bf(f);
    c_W2h[idx] = h; c_W2l[idx] = f2bf(f - bf2f(h));
    return;
  }
  j -= PREP_W2;
  if      (j <  256) c_as1f[j]        = ld(ps.p[1], j);
  else if (j <  512) c_ad1f[j - 256]  = ld(ps.p[2], j - 256);
  else if (j <  768) c_b1f [j - 512]  = ld(ps.p[3], j - 512);
  else if (j <  896) c_as2f[j - 768]  = ld(ps.p[5], j - 768);
  else if (j < 1024) c_ad2f[j - 896]  = ld(ps.p[6], j - 896);
  else if (j < 1152) c_b2f [j - 1024] = ld(ps.p[7], j - 1024);
}

__global__ __launch_bounds__(256) void gemm1_k(const void* __restrict__ xsrc,
                                               const int* __restrict__ ei){
  if (blockIdx.x >= GEMM1_BLKS){
    int e = (int)(blockIdx.x - GEMM1_BLKS) * 256 + (int)threadIdx.x;
    if (e < N_EDGES){
      int s, d;
      edge_sd(ei, e, s, d);
      int pos = atomicAdd(&g_cursor[d], 1);
      if (pos < CAP) g_srcidx[(size_t)d * CAP + pos] = s;
    }
    return;
  }

  __shared__ float s_ps[4][32], s_pd[4][32];
  const bool isf32 = (g_isf32 != 0);
  int wid  = (int)(threadIdx.x >> 6);
  int lane = (int)(threadIdx.x & 63);
  int kgrp = lane >> 4, cl = lane & 15;
  int mbase = blockIdx.x * 32;

  f32x4 acc[2][4];
#pragma unroll
  for (int m = 0; m < 2; ++m)
#pragma unroll
    for (int n = 0; n < 4; ++n) acc[m][n] = (f32x4){0.f, 0.f, 0.f, 0.f};

  for (int kt = 0; kt < 8; ++kt){
    int kbase = kt * 32 + kgrp * 8;
    bf16x8 ah[2], al[2];
    if (isf32){
      const float* Xf = (const float*)xsrc;
#pragma unroll
      for (int m = 0; m < 2; ++m){
        const float4* xp = (const float4*)(Xf + (size_t)(mbase + m * 16 + cl) * 256 + kbase);
        float4 v0 = xp[0], v1 = xp[1];
        float vals[8] = {v0.x, v0.y, v0.z, v0.w, v1.x, v1.y, v1.z, v1.w};
#pragma unroll
        for (int j = 0; j < 8; ++j){
          unsigned short h = f2bf(vals[j]);
          ah[m][j] = (short)h;
          al[m][j] = (short)f2bf(vals[j] - bf2f(h));
        }
      }
    } else {
      const unsigned short* Xb = (const unsigned short*)xsrc;
#pragma unroll
      for (int m = 0; m < 2; ++m){
        ah[m] = *(const bf16x8*)(Xb + (size_t)(mbase + m * 16 + cl) * 256 + kbase);
        al[m] = (bf16x8){0,0,0,0,0,0,0,0};
      }
    }
#pragma unroll
    for (int nn = 0; nn < 4; ++nn){
      int nt = wid * 4 + nn;
      size_t wi = ((size_t)(kt * 16 + nt) * 64 + lane) * 8;
      bf16x8 bh = *(const bf16x8*)(c_W1h + wi);
      bf16x8 bl = *(const bf16x8*)(c_W1l + wi);
#pragma unroll
      for (int m = 0; m < 2; ++m){
        acc[m][nn] = __builtin_amdgcn_mfma_f32_16x16x32_bf16(ah[m], bh, acc[m][nn], 0, 0, 0);
        acc[m][nn] = __builtin_amdgcn_mfma_f32_16x16x32_bf16(ah[m], bl, acc[m][nn], 0, 0, 0);
        acc[m][nn] = __builtin_amdgcn_mfma_f32_16x16x32_bf16(al[m], bh, acc[m][nn], 0, 0, 0);
      }
    }
  }

  float asv[4], adv[4];
#pragma unroll
  for (int nn = 0; nn < 4; ++nn){
    int col = (wid * 4 + nn) * 16 + cl;
    asv[nn] = c_as1f[col]; adv[nn] = c_ad1f[col];
  }
#pragma unroll
  for (int m = 0; m < 2; ++m){
#pragma unroll
    for (int i = 0; i < 4; ++i){
      int rl = m * 16 + kgrp * 4 + i;
      int row = mbase + rl;
      float ps = 0.f, pd = 0.f;
#pragma unroll
      for (int nn = 0; nn < 4; ++nn){
        int col = (wid * 4 + nn) * 16 + cl;
        float v = acc[m][nn][i];
        g_h1b[(size_t)row * C_HID + col] = f2bf(v);
        ps += v * asv[nn]; pd += v * adv[nn];
      }
      ps += __shfl_xor(ps, 1);  pd += __shfl_xor(pd, 1);
      ps += __shfl_xor(ps, 2);  pd += __shfl_xor(pd, 2);
      ps += __shfl_xor(ps, 4);  pd += __shfl_xor(pd, 4);
      ps += __shfl_xor(ps, 8);  pd += __shfl_xor(pd, 8);
      if (cl == 0){ s_ps[wid][rl] = ps; s_pd[wid][rl] = pd; }
    }
  }
  __syncthreads();
  if (threadIdx.x < 32){
    int r = (int)threadIdx.x;
    g_alps1[mbase + r] = s_ps[0][r] + s_ps[1][r] + s_ps[2][r] + s_ps[3][r];
    g_alpd1[mbase + r] = s_pd[0][r] + s_pd[1][r] + s_pd[2][r] + s_pd[3][r];
  }
}

__global__ __launch_bounds__(256) void aggemm_k(){
  __shared__ __align__(16) unsigned short s_hi[16 * AGG_PAD];
  __shared__ __align__(16) unsigned short s_lo[16 * AGG_PAD];
  __shared__ float s_ps[4][16], s_pd[4][16];

  int lane = (int)(threadIdx.x & 63);
  int wid  = (int)(threadIdx.x >> 6);
  int nb   = blockIdx.x * 16;
  const uint2* H2 = (const uint2*)g_h1b;

  for (int q = 0; q < 4; ++q){
    int n = nb + wid * 4 + q;
    int len = g_cursor[n]; if (len > CAP) len = CAP;
    int i0 = n * CAP, i1 = i0 + len;
    float adn = g_alpd1[n];
    float dpart = 0.f;
    float a0 = 0.f, a1 = 0.f, a2 = 0.f, a3 = 0.f;

    {
      float es = g_alps1[n] + adn;
      es = (es > 0.f) ? es : NEG_SLOPE * es;
      float wself = __expf(es);
      if (lane == 0) dpart += wself;
      uint2 p = H2[(size_t)n * 64 + lane];
      ACC4(p, wself)
    }

    for (int base = i0; base < i1; base += 64){
      int nv = i1 - base; if (nv > 64) nv = 64;
      int sv = 0; float wv = 0.f;
      if (lane < nv){
        sv = g_srcidx[base + lane];
        float e = g_alps1[sv] + adn;
        e = (e > 0.f) ? e : NEG_SLOPE * e;
        wv = __expf(e);
      }
      dpart += wv;
      int j = 0;
      for (; j + 8 <= nv; j += 8){
        int s0 = __shfl(sv, j),     s1 = __shfl(sv, j + 1);
        int s2 = __shfl(sv, j + 2), s3 = __shfl(sv, j + 3);
        int s4 = __shfl(sv, j + 4), s5 = __shfl(sv, j + 5);
        int s6 = __shfl(sv, j + 6), s7 = __shfl(sv, j + 7);
        float w0 = __shfl(wv, j),     w1 = __shfl(wv, j + 1);
        float w2 = __shfl(wv, j + 2), w3 = __shfl(wv, j + 3);
        float w4 = __shfl(wv, j + 4), w5 = __shfl(wv, j + 5);
        float w6 = __shfl(wv, j + 6), w7 = __shfl(wv, j + 7);
        uint2 p0 = H2[(size_t)s0 * 64 + lane];
        uint2 p1 = H2[(size_t)s1 * 64 + lane];
        uint2 p2 = H2[(size_t)s2 * 64 + lane];
        uint2 p3 = H2[(size_t)s3 * 64 + lane];
        uint2 p4 = H2[(size_t)s4 * 64 + lane];
        uint2 p5 = H2[(size_t)s5 * 64 + lane];
        uint2 p6 = H2[(size_t)s6 * 64 + lane];
        uint2 p7 = H2[(size_t)s7 * 64 + lane];
        ACC4(p0, w0) ACC4(p1, w1) ACC4(p2, w2) ACC4(p3, w3)
        ACC4(p4, w4) ACC4(p5, w5) ACC4(p6, w6) ACC4(p7, w7)
      }
      for (; j + 4 <= nv; j += 4){
        int s0 = __shfl(sv, j),     s1 = __shfl(sv, j + 1);
        int s2 = __shfl(sv, j + 2), s3 = __shfl(sv, j + 3);
        float w0 = __shfl(wv, j),     w1 = __shfl(wv, j + 1);
        float w2 = __shfl(wv, j + 2), w3 = __shfl(wv, j + 3);
        uint2 p0 = H2[(size_t)s0 * 64 + lane];
        uint2 p1 = H2[(size_t)s1 * 64 + lane];
        uint2 p2 = H2[(size_t)s2 * 64 + lane];
        uint2 p3 = H2[(size_t)s3 * 64 + lane];
        ACC4(p0, w0) ACC4(p1, w1) ACC4(p2, w2) ACC4(p3, w3)
      }
      for (; j < nv; ++j){
        int s = __shfl(sv, j);
        float w = __shfl(wv, j);
        uint2 p = H2[(size_t)s * 64 + lane];
        ACC4(p, w)
      }
    }

    float den = dpart;
#pragma unroll
    for (int o = 32; o > 0; o >>= 1) den += __shfl_xor(den, o, 64);
    float inv = 1.f / den;

    float o0 = a0 * inv + c_b1f[4 * lane];
    float o1 = a1 * inv + c_b1f[4 * lane + 1];
    float o2 = a2 * inv + c_b1f[4 * lane + 2];
    float o3 = a3 * inv + c_b1f[4 * lane + 3];
    o0 = fmaxf(o0, 0.f); o1 = fmaxf(o1, 0.f);
    o2 = fmaxf(o2, 0.f); o3 = fmaxf(o3, 0.f);
    unsigned short h0 = f2bf(o0), h1 = f2bf(o1), h2 = f2bf(o2), h3 = f2bf(o3);
    uint2 ph, pl;
    ph.x = (unsigned)h0 | ((unsigned)h1 << 16);
    ph.y = (unsigned)h2 | ((unsigned)h3 << 16);
    pl.x = (unsigned)f2bf(o0 - bf2f(h0)) | ((unsigned)f2bf(o1 - bf2f(h1)) << 16);
    pl.y = (unsigned)f2bf(o2 - bf2f(h2)) | ((unsigned)f2bf(o3 - bf2f(h3)) << 16);
    int r = wid * 4 + q;
    *(uint2*)&s_hi[r * AGG_PAD + 4 * lane] = ph;
    *(uint2*)&s_lo[r * AGG_PAD + 4 * lane] = pl;
  }
  __syncthreads();

  int kgrp = lane >> 4, cl = lane & 15;
  f32x4 acc[2];
  acc[0] = (f32x4){0.f, 0.f, 0.f, 0.f};
  acc[1] = (f32x4){0.f, 0.f, 0.f, 0.f};
  for (int kt = 0; kt < 8; ++kt){
    int rb = cl * AGG_PAD + kt * 32 + kgrp * 8;
    bf16x8 ah = *(const bf16x8*)&s_hi[rb];
    bf16x8 al = *(const bf16x8*)&s_lo[rb];
#pragma unroll
    for (int nn = 0; nn < 2; ++nn){
      int nt = wid * 2 + nn;
      size_t wi = ((size_t)(kt * 8 + nt) * 64 + lane) * 8;
      bf16x8 bh = *(const bf16x8*)(c_W2h + wi);
      bf16x8 bl = *(const bf16x8*)(c_W2l + wi);
      acc[nn] = __builtin_amdgcn_mfma_f32_16x16x32_bf16(ah, bh, acc[nn], 0, 0, 0);
      acc[nn] = __builtin_amdgcn_mfma_f32_16x16x32_bf16(ah, bl, acc[nn], 0, 0, 0);
      acc[nn] = __builtin_amdgcn_mfma_f32_16x16x32_bf16(al, bh, acc[nn], 0, 0, 0);
    }
  }

  float asv[2], adv[2];
#pragma unroll
  for (int nn = 0; nn < 2; ++nn){
    int col = (wid * 2 + nn) * 16 + cl;
    asv[nn] = c_as2f[col]; adv[nn] = c_ad2f[col];
  }
#pragma unroll
  for (int i = 0; i < 4; ++i){
    int row = nb + kgrp * 4 + i;
    float ps = 0.f, pd = 0.f;
#pragma unroll
    for (int nn = 0; nn < 2; ++nn){
      int col = (wid * 2 + nn) * 16 + cl;
      float v = acc[nn][i];
      g_h2b[(size_t)row * C_OUT + col] = f2bf(v);
      ps += v * asv[nn]; pd += v * adv[nn];
    }
    ps += __shfl_xor(ps, 1);  pd += __shfl_xor(pd, 1);
    ps += __shfl_xor(ps, 2);  pd += __shfl_xor(pd, 2);
    ps += __shfl_xor(ps, 4);  pd += __shfl_xor(pd, 4);
    ps += __shfl_xor(ps, 8);  pd += __shfl_xor(pd, 8);
    if (cl == 0){ s_ps[wid][kgrp * 4 + i] = ps; s_pd[wid][kgrp * 4 + i] = pd; }
  }
  __syncthreads();
  if (threadIdx.x < 16){
    int r = (int)threadIdx.x;
    g_alps2[nb + r] = s_ps[0][r] + s_ps[1][r] + s_ps[2][r] + s_ps[3][r];
    g_alpd2[nb + r] = s_pd[0][r] + s_pd[1][r] + s_pd[2][r] + s_pd[3][r];
  }
}

__global__ __launch_bounds__(256) void agg2_k(float* OUT){
  int lane = (int)(threadIdx.x & 63);
  int n = blockIdx.x * 4 + (int)(threadIdx.x >> 6);
  int len = g_cursor[n]; if (len > CAP) len = CAP;
  int i0 = n * CAP, i1 = i0 + len;
  float adn = g_alpd2[n];
  float dpart = 0.f;
  float a0 = 0.f, a1 = 0.f;
  const unsigned int* H1 = (const unsigned int*)g_h2b;

  {
    float es = g_alps2[n] + adn;
    es = (es > 0.f) ? es : NEG_SLOPE * es;
    float wself = __expf(es);
    if (lane == 0) dpart += wself;
    unsigned int p = H1[(size_t)n * 64 + lane];
    ACC2(p, wself)
  }

  for (int base = i0; base < i1; base += 64){
    int nv = i1 - base; if (nv > 64) nv = 64;
    int sv = 0; float wv = 0.f;
    if (lane < nv){
      sv = g_srcidx[base + lane];
      float e = g_alps2[sv] + adn;
      e = (e > 0.f) ? e : NEG_SLOPE * e;
      wv = __expf(e);
    }
    dpart += wv;
    int j = 0;
    for (; j + 8 <= nv; j += 8){
      int s0 = __shfl(sv, j),     s1 = __shfl(sv, j + 1);
      int s2 = __shfl(sv, j + 2), s3 = __shfl(sv, j + 3);
      int s4 = __shfl(sv, j + 4), s5 = __shfl(sv, j + 5);
      int s6 = __shfl(sv, j + 6), s7 = __shfl(sv, j + 7);
      float w0 = __shfl(wv, j),     w1 = __shfl(wv, j + 1);
      float w2 = __shfl(wv, j + 2), w3 = __shfl(wv, j + 3);
      float w4 = __shfl(wv, j + 4), w5 = __shfl(wv, j + 5);
      float w6 = __shfl(wv, j + 6), w7 = __shfl(wv, j + 7);
      unsigned int p0 = H1[(size_t)s0 * 64 + lane];
      unsigned int p1 = H1[(size_t)s1 * 64 + lane];
      unsigned int p2 = H1[(size_t)s2 * 64 + lane];
      unsigned int p3 = H1[(size_t)s3 * 64 + lane];
      unsigned int p4 = H1[(size_t)s4 * 64 + lane];
      unsigned int p5 = H1[(size_t)s5 * 64 + lane];
      unsigned int p6 = H1[(size_t)s6 * 64 + lane];
      unsigned int p7 = H1[(size_t)s7 * 64 + lane];
      ACC2(p0, w0) ACC2(p1, w1) ACC2(p2, w2) ACC2(p3, w3)
      ACC2(p4, w4) ACC2(p5, w5) ACC2(p6, w6) ACC2(p7, w7)
    }
    for (; j + 4 <= nv; j += 4){
      int s0 = __shfl(sv, j),     s1 = __shfl(sv, j + 1);
      int s2 = __shfl(sv, j + 2), s3 = __shfl(sv, j + 3);
      float w0 = __shfl(wv, j),     w1 = __shfl(wv, j + 1);
      float w2 = __shfl(wv, j + 2), w3 = __shfl(wv, j + 3);
      unsigned int p0 = H1[(size_t)s0 * 64 + lane];
      unsigned int p1 = H1[(size_t)s1 * 64 + lane];
      unsigned int p2 = H1[(size_t)s2 * 64 + lane];
      unsigned int p3 = H1[(size_t)s3 * 64 + lane];
      ACC2(p0, w0) ACC2(p1, w1) ACC2(p2, w2) ACC2(p3, w3)
    }
    for (; j < nv; ++j){
      int s = __shfl(sv, j);
      float w = __shfl(wv, j);
      unsigned int p = H1[(size_t)s * 64 + lane];
      ACC2(p, w)
    }
  }

  float den = dpart;
#pragma unroll
  for (int o = 32; o > 0; o >>= 1) den += __shfl_xor(den, o, 64);
  float inv = 1.f / den;

  float2 o;
  o.x = a0 * inv + c_b2f[2 * lane];
  o.y = a1 * inv + c_b2f[2 * lane + 1];
  ((float2*)OUT)[(size_t)n * 64 + lane] = o;
}

extern "C" void kernel_launch(void* const* d_in, const int* in_sizes, int n_in,
                              void* d_out, int out_size, void* d_ws, size_t ws_size,
                              hipStream_t stream){
  (void)in_sizes; (void)n_in; (void)out_size; (void)d_ws; (void)ws_size;
  const void* x  = d_in[0];
  const int*  ei = (const int*)d_in[1];
  float* out = (float*)d_out;

  Ptrs ps;
  ps.p[0] = d_in[2]; ps.p[1] = d_in[3]; ps.p[2] = d_in[4]; ps.p[3] = d_in[5];
  ps.p[4] = d_in[6]; ps.p[5] = d_in[7]; ps.p[6] = d_in[8]; ps.p[7] = d_in[9];

  // ---- cooperative mega-kernel path, grid sized for GUARANTEED residency ----
  // R4 evidence: occupancy API over-reports 2x on gfx950 (ignores AGPR share
  // of the unified register file); launching at its value caused CWSR
  // time-slicing (OccupancyPercent 48.7%, 850us idle spin). Use (nb/2 - 1)
  // blocks/CU (expected 3/CU = 768 blocks) -- queues rebalance any grid size.
  static int coop_grid = -1;
  if (coop_grid < 0){
    int nb = 0, ncu = 0, dev = 0;
    (void)hipGetDevice(&dev);
    if (hipOccupancyMaxActiveBlocksPerMultiprocessor(&nb, fused_k, 256, 0) != hipSuccess) nb = 0;
    if (hipDeviceGetAttribute(&ncu, hipDeviceAttributeMultiprocessorCount, dev) != hipSuccess || ncu <= 0)
      ncu = 256;
    int per_cu = nb / 2 - 1;
    if (per_cu < 1) per_cu = (nb > 0) ? 1 : 0;
    coop_grid = per_cu * ncu;
  }
  if (coop_grid > 0){
    const unsigned int* xw = (const unsigned int*)x;
    void* args[4] = { (void*)&xw, (void*)&ei, (void*)&out, (void*)&ps };
    hipError_t err = hipLaunchCooperativeKernel((const void*)fused_k,
                                                dim3((unsigned)coop_grid), dim3(256),
                                                args, 0, stream);
    if (err == hipSuccess) return;
    coop_grid = 0;                 // cooperative unsupported: fall back permanently
  }

  // ---- fallback: proven R3 five-kernel pipeline ----
  prep_k<<<(PREP_T + 255) / 256, 256, 0, stream>>>((const unsigned int*)x, ei, ps);
  gemm1_k<<<GEMM1_BLKS + SCAT_BLKS, 256, 0, stream>>>(x, ei);
  aggemm_k<<<AGGEMM_BLKS, 256, 0, stream>>>();
  agg2_k<<<AGG2_BLKS, 256, 0, stream>>>(out);
}

// Round 6
// 165.673 us; speedup vs baseline: 3.7550x; 2.9545x over previous
//
#include <hip/hip_runtime.h>
#include <math.h>

#define N_NODES 20000
#define N_EDGES 320000
#define C_IN  256
#define C_HID 256
#define C_OUT 128
#define NEG_SLOPE 0.2f
#define CAP   256   // padded-CSR slots per node (real edges only; self-loop implicit)
#define GEMM1_BLKS (N_NODES / 32)          // 625
#define SCAT_BLKS  ((N_EDGES + 255) / 256) // 1250
#define AGG_PAD 280 // 256 + 24: LDS row stride (560 B = 16B-aligned, 8 bank-start groups)

typedef __attribute__((ext_vector_type(8))) short bf16x8;
typedef __attribute__((ext_vector_type(4))) float f32x4;

// ---- all scratch in module globals (ws_size unknown; globals are safe) ----
__device__ __align__(16) unsigned short c_W1h[C_IN * C_HID], c_W1l[C_IN * C_HID];
__device__ __align__(16) unsigned short c_W2h[C_HID * C_OUT], c_W2l[C_HID * C_OUT];
__device__ float c_as1f[C_HID], c_ad1f[C_HID], c_b1f[C_HID];
__device__ float c_as2f[C_OUT], c_ad2f[C_OUT], c_b2f[C_OUT];
__device__ __align__(16) unsigned short g_h1b[(size_t)N_NODES * C_HID]; // h1 bf16
__device__ __align__(16) unsigned short g_h2b[(size_t)N_NODES * C_OUT]; // h2 bf16
__device__ float g_alps1[N_NODES], g_alpd1[N_NODES];
__device__ float g_alps2[N_NODES], g_alpd2[N_NODES];
__device__ int   g_cursor[N_NODES];            // per-node real-edge count
__device__ int   g_srcidx[(size_t)N_NODES * CAP];
__device__ int   g_is64;    // edge_index arrived as raw int64 words
__device__ int   g_isf32;   // float inputs arrived as raw fp32 words

__device__ __forceinline__ float bf2f(unsigned short b){
  unsigned int u = ((unsigned int)b) << 16;
  return __builtin_bit_cast(float, u);
}
__device__ __forceinline__ unsigned short f2bf(float f){
  unsigned int u = __builtin_bit_cast(unsigned int, f);
  u += 0x7fffu + ((u >> 16) & 1u);   // round-to-nearest-even
  return (unsigned short)(u >> 16);
}
__device__ __forceinline__ int clampi(int v){
  v = v < 0 ? 0 : v;
  return v >= N_NODES ? N_NODES - 1 : v;
}
__device__ __forceinline__ void edge_sd(const int* ei, int e, int& s, int& d){
  if (g_is64){ s = ei[2 * e]; d = ei[2 * (N_EDGES + e)]; }
  else       { s = ei[e];     d = ei[N_EDGES + e]; }
  s = clampi(s); d = clampi(d);
}

struct Ptrs { const void* p[8]; };

// pack (k, n) of a [K][Nc] weight into MFMA B-fragment order
__device__ __forceinline__ int wpack(int k, int n, int Nc){
  return (((k >> 5) * (Nc / 16) + (n >> 4)) * 64 + (((k >> 3) & 3) * 16 + (n & 15))) * 8 + (k & 7);
}

// =======================================================================
// prep_k: probe publish + cursor zero + weight pack, ONE dispatch.
// (alpha accumulators need no zeroing: gemm1/aggemm plain-store them)
// =======================================================================
#define PREP_Z  N_NODES
#define PREP_W1 (C_IN * C_HID)
#define PREP_W2 (C_HID * C_OUT)
#define PREP_T  (PREP_Z + PREP_W1 + PREP_W2 + 2 * C_HID + C_HID + 2 * C_OUT + C_OUT)

__global__ void prep_k(const unsigned int* __restrict__ xw,
                       const int* __restrict__ ei, Ptrs ps){
  __shared__ int s_isf32;
  if (threadIdx.x < 64){
    int lane = (int)threadIdx.x, cnt = 0;
    for (int j = lane; j < 256; j += 64){
      unsigned int e = (xw[j] >> 7) & 0xFFu;
      if (e >= 0x60u && e <= 0x8Fu) ++cnt;
    }
#pragma unroll
    for (int o = 32; o > 0; o >>= 1) cnt += __shfl_xor(cnt, o, 64);
    if (lane == 0) s_isf32 = (cnt < 200) ? 1 : 0;  // bf16 ~256 in-win; fp32 ~48
  }
  __syncthreads();
  const int isf32 = s_isf32;

  if (blockIdx.x == 0 && threadIdx.x < 64){        // publish for later dispatches
    unsigned long long anybad = __ballot(ei[2 * (int)threadIdx.x + 1] != 0);
    if (threadIdx.x == 0){ g_isf32 = isf32; g_is64 = (anybad == 0ULL) ? 1 : 0; }
  }

  int tid = (int)(blockIdx.x * blockDim.x + threadIdx.x);
  if (tid < PREP_Z){
    g_cursor[tid] = 0;
    return;
  }
  int j = tid - PREP_Z;
  auto ld = [&](const void* p, int i) -> float {
    return isf32 ? ((const float*)p)[i] : bf2f(((const unsigned short*)p)[i]);
  };
  if (j < PREP_W1){
    float f = ld(ps.p[0], j);
    int k = j / C_HID, n = j % C_HID;
    int idx = wpack(k, n, C_HID);
    unsigned short h = f2bf(f);
    c_W1h[idx] = h; c_W1l[idx] = f2bf(f - bf2f(h));
    return;
  }
  j -= PREP_W1;
  if (j < PREP_W2){
    float f = ld(ps.p[4], j);
    int k = j / C_OUT, n = j % C_OUT;
    int idx = wpack(k, n, C_OUT);
    unsigned short h = f2bf(f);
    c_W2h[idx] = h; c_W2l[idx] = f2bf(f - bf2f(h));
    return;
  }
  j -= PREP_W2;
  if      (j <  256) c_as1f[j]        = ld(ps.p[1], j);
  else if (j <  512) c_ad1f[j - 256]  = ld(ps.p[2], j - 256);
  else if (j <  768) c_b1f [j - 512]  = ld(ps.p[3], j - 512);
  else if (j <  896) c_as2f[j - 768]  = ld(ps.p[5], j - 768);
  else if (j < 1024) c_ad2f[j - 896]  = ld(ps.p[6], j - 896);
  else if (j < 1152) c_b2f [j - 1024] = ld(ps.p[7], j - 1024);
}

// ---------------- layer-1 split-bf16 MFMA GEMM + fused alpha epilogue ----------------
// Blocks [0,625) do gemm1; blocks [625,1875) scatter edges into the padded CSR
// (independent work, overlapped in one dispatch).
// Each gemm block owns complete rows (all 256 cols) -> alpha sums via LDS
// cross-wave reduce + plain store: no atomics, no pre-zeroing dependency.
__global__ __launch_bounds__(256) void gemm1_k(const void* __restrict__ xsrc,
                                               const int* __restrict__ ei){
  if (blockIdx.x >= GEMM1_BLKS){   // ---- scatter part ----
    int e = (int)(blockIdx.x - GEMM1_BLKS) * 256 + (int)threadIdx.x;
    if (e < N_EDGES){
      int s, d;
      edge_sd(ei, e, s, d);
      int pos = atomicAdd(&g_cursor[d], 1);
      if (pos < CAP) g_srcidx[(size_t)d * CAP + pos] = s;  // clamp: memory-safe
    }
    return;
  }

  __shared__ float s_ps[4][32], s_pd[4][32];

  const bool isf32 = (g_isf32 != 0);
  int wid  = (int)(threadIdx.x >> 6);
  int lane = (int)(threadIdx.x & 63);
  int kgrp = lane >> 4, cl = lane & 15;
  int mbase = blockIdx.x * 32;

  f32x4 acc[2][4];
#pragma unroll
  for (int m = 0; m < 2; ++m)
#pragma unroll
    for (int n = 0; n < 4; ++n) acc[m][n] = (f32x4){0.f, 0.f, 0.f, 0.f};

  for (int kt = 0; kt < 8; ++kt){
    int kbase = kt * 32 + kgrp * 8;
    bf16x8 ah[2], al[2];
    if (isf32){
      const float* Xf = (const float*)xsrc;
#pragma unroll
      for (int m = 0; m < 2; ++m){
        const float4* xp = (const float4*)(Xf + (size_t)(mbase + m * 16 + cl) * 256 + kbase);
        float4 v0 = xp[0], v1 = xp[1];
        float vals[8] = {v0.x, v0.y, v0.z, v0.w, v1.x, v1.y, v1.z, v1.w};
#pragma unroll
        for (int j = 0; j < 8; ++j){
          unsigned short h = f2bf(vals[j]);
          ah[m][j] = (short)h;
          al[m][j] = (short)f2bf(vals[j] - bf2f(h));
        }
      }
    } else {  // bf16 input: lo part is zero
      const unsigned short* Xb = (const unsigned short*)xsrc;
#pragma unroll
      for (int m = 0; m < 2; ++m){
        ah[m] = *(const bf16x8*)(Xb + (size_t)(mbase + m * 16 + cl) * 256 + kbase);
        al[m] = (bf16x8){0,0,0,0,0,0,0,0};
      }
    }
#pragma unroll
    for (int nn = 0; nn < 4; ++nn){
      int nt = wid * 4 + nn;
      size_t wi = ((size_t)(kt * 16 + nt) * 64 + lane) * 8;   // Nc/16 = 16
      bf16x8 bh = *(const bf16x8*)(c_W1h + wi);
      bf16x8 bl = *(const bf16x8*)(c_W1l + wi);
#pragma unroll
      for (int m = 0; m < 2; ++m){
        acc[m][nn] = __builtin_amdgcn_mfma_f32_16x16x32_bf16(ah[m], bh, acc[m][nn], 0, 0, 0);
        acc[m][nn] = __builtin_amdgcn_mfma_f32_16x16x32_bf16(ah[m], bl, acc[m][nn], 0, 0, 0);
        acc[m][nn] = __builtin_amdgcn_mfma_f32_16x16x32_bf16(al[m], bh, acc[m][nn], 0, 0, 0);
      }
    }
  }

  float asv[4], adv[4];
#pragma unroll
  for (int nn = 0; nn < 4; ++nn){
    int col = (wid * 4 + nn) * 16 + cl;
    asv[nn] = c_as1f[col]; adv[nn] = c_ad1f[col];
  }
#pragma unroll
  for (int m = 0; m < 2; ++m){
#pragma unroll
    for (int i = 0; i < 4; ++i){
      int rl = m * 16 + kgrp * 4 + i;        // row-local in [0,32)
      int row = mbase + rl;
      float ps = 0.f, pd = 0.f;
#pragma unroll
      for (int nn = 0; nn < 4; ++nn){
        int col = (wid * 4 + nn) * 16 + cl;
        float v = acc[m][nn][i];
        g_h1b[(size_t)row * C_HID + col] = f2bf(v);
        ps += v * asv[nn]; pd += v * adv[nn];
      }
      ps += __shfl_xor(ps, 1);  pd += __shfl_xor(pd, 1);
      ps += __shfl_xor(ps, 2);  pd += __shfl_xor(pd, 2);
      ps += __shfl_xor(ps, 4);  pd += __shfl_xor(pd, 4);
      ps += __shfl_xor(ps, 8);  pd += __shfl_xor(pd, 8);
      if (cl == 0){ s_ps[wid][rl] = ps; s_pd[wid][rl] = pd; }
    }
  }
  __syncthreads();
  if (threadIdx.x < 32){
    int r = (int)threadIdx.x;
    g_alps1[mbase + r] = s_ps[0][r] + s_ps[1][r] + s_ps[2][r] + s_ps[3][r];
    g_alpd1[mbase + r] = s_pd[0][r] + s_pd[1][r] + s_pd[2][r] + s_pd[3][r];
  }
}

#define ACC4(p, ww) { \
  a0 += (ww) * bf2f((unsigned short)((p).x & 0xFFFFu)); \
  a1 += (ww) * bf2f((unsigned short)((p).x >> 16)); \
  a2 += (ww) * bf2f((unsigned short)((p).y & 0xFFFFu)); \
  a3 += (ww) * bf2f((unsigned short)((p).y >> 16)); }

#define ACC2(p, ww) { \
  a0 += (ww) * bf2f((unsigned short)((p) & 0xFFFFu)); \
  a1 += (ww) * bf2f((unsigned short)((p) >> 16)); }

// =======================================================================
// aggemm_k: layer-1 softmax+aggregation FUSED with gemm2 (R1-proven bodies).
// Gather is FULL-WAVE: 64 lanes x 8B = one 512B h1 row per load instruction;
// zero inert lanes, zero extra traffic (R2's pairing experiment showed the
// phase is L2/L3-traffic-bound, so traffic discipline wins over issue count).
// =======================================================================
__global__ __launch_bounds__(256) void aggemm_k(){
  __shared__ __align__(16) unsigned short s_hi[16 * AGG_PAD];
  __shared__ __align__(16) unsigned short s_lo[16 * AGG_PAD];
  __shared__ float s_ps[4][16], s_pd[4][16];

  int lane = (int)(threadIdx.x & 63);
  int wid  = (int)(threadIdx.x >> 6);
  int nb   = blockIdx.x * 16;
  const uint2* H2 = (const uint2*)g_h1b;

  // ---- phase 1: each wave aggregates 4 nodes ----
  for (int q = 0; q < 4; ++q){
    int n = nb + wid * 4 + q;
    int len = g_cursor[n]; if (len > CAP) len = CAP;
    int i0 = n * CAP, i1 = i0 + len;
    float adn = g_alpd1[n];
    float dpart = 0.f;
    float a0 = 0.f, a1 = 0.f, a2 = 0.f, a3 = 0.f;

    { // implicit self-loop: source row = n
      float es = g_alps1[n] + adn;
      es = (es > 0.f) ? es : NEG_SLOPE * es;
      float wself = __expf(es);
      if (lane == 0) dpart += wself;
      uint2 p = H2[(size_t)n * 64 + lane];
      ACC4(p, wself)
    }

    for (int base = i0; base < i1; base += 64){
      int nv = i1 - base; if (nv > 64) nv = 64;
      int sv = 0; float wv = 0.f;
      if (lane < nv){
        sv = g_srcidx[base + lane];
        float e = g_alps1[sv] + adn;
        e = (e > 0.f) ? e : NEG_SLOPE * e;
        wv = __expf(e);
      }
      dpart += wv;
      int j = 0;
      for (; j + 8 <= nv; j += 8){
        int s0 = __shfl(sv, j),     s1 = __shfl(sv, j + 1);
        int s2 = __shfl(sv, j + 2), s3 = __shfl(sv, j + 3);
        int s4 = __shfl(sv, j + 4), s5 = __shfl(sv, j + 5);
        int s6 = __shfl(sv, j + 6), s7 = __shfl(sv, j + 7);
        float w0 = __shfl(wv, j),     w1 = __shfl(wv, j + 1);
        float w2 = __shfl(wv, j + 2), w3 = __shfl(wv, j + 3);
        float w4 = __shfl(wv, j + 4), w5 = __shfl(wv, j + 5);
        float w6 = __shfl(wv, j + 6), w7 = __shfl(wv, j + 7);
        uint2 p0 = H2[(size_t)s0 * 64 + lane];
        uint2 p1 = H2[(size_t)s1 * 64 + lane];
        uint2 p2 = H2[(size_t)s2 * 64 + lane];
        uint2 p3 = H2[(size_t)s3 * 64 + lane];
        uint2 p4 = H2[(size_t)s4 * 64 + lane];
        uint2 p5 = H2[(size_t)s5 * 64 + lane];
        uint2 p6 = H2[(size_t)s6 * 64 + lane];
        uint2 p7 = H2[(size_t)s7 * 64 + lane];
        ACC4(p0, w0) ACC4(p1, w1) ACC4(p2, w2) ACC4(p3, w3)
        ACC4(p4, w4) ACC4(p5, w5) ACC4(p6, w6) ACC4(p7, w7)
      }
      for (; j + 4 <= nv; j += 4){
        int s0 = __shfl(sv, j),     s1 = __shfl(sv, j + 1);
        int s2 = __shfl(sv, j + 2), s3 = __shfl(sv, j + 3);
        float w0 = __shfl(wv, j),     w1 = __shfl(wv, j + 1);
        float w2 = __shfl(wv, j + 2), w3 = __shfl(wv, j + 3);
        uint2 p0 = H2[(size_t)s0 * 64 + lane];
        uint2 p1 = H2[(size_t)s1 * 64 + lane];
        uint2 p2 = H2[(size_t)s2 * 64 + lane];
        uint2 p3 = H2[(size_t)s3 * 64 + lane];
        ACC4(p0, w0) ACC4(p1, w1) ACC4(p2, w2) ACC4(p3, w3)
      }
      for (; j < nv; ++j){
        int s = __shfl(sv, j);
        float w = __shfl(wv, j);
        uint2 p = H2[(size_t)s * 64 + lane];
        ACC4(p, w)
      }
    }

    float den = dpart;
#pragma unroll
    for (int o = 32; o > 0; o >>= 1) den += __shfl_xor(den, o, 64);
    float inv = 1.f / den;

    float o0 = a0 * inv + c_b1f[4 * lane];
    float o1 = a1 * inv + c_b1f[4 * lane + 1];
    float o2 = a2 * inv + c_b1f[4 * lane + 2];
    float o3 = a3 * inv + c_b1f[4 * lane + 3];
    o0 = fmaxf(o0, 0.f); o1 = fmaxf(o1, 0.f);
    o2 = fmaxf(o2, 0.f); o3 = fmaxf(o3, 0.f);
    unsigned short h0 = f2bf(o0), h1 = f2bf(o1), h2 = f2bf(o2), h3 = f2bf(o3);
    uint2 ph, pl;
    ph.x = (unsigned)h0 | ((unsigned)h1 << 16);
    ph.y = (unsigned)h2 | ((unsigned)h3 << 16);
    pl.x = (unsigned)f2bf(o0 - bf2f(h0)) | ((unsigned)f2bf(o1 - bf2f(h1)) << 16);
    pl.y = (unsigned)f2bf(o2 - bf2f(h2)) | ((unsigned)f2bf(o3 - bf2f(h3)) << 16);
    int r = wid * 4 + q;
    *(uint2*)&s_hi[r * AGG_PAD + 4 * lane] = ph;
    *(uint2*)&s_lo[r * AGG_PAD + 4 * lane] = pl;
  }
  __syncthreads();

  // ---- phase 2: gemm2 tile, rows [nb, nb+16), cols [0,128), K=256 ----
  int kgrp = lane >> 4, cl = lane & 15;
  f32x4 acc[2];
  acc[0] = (f32x4){0.f, 0.f, 0.f, 0.f};
  acc[1] = (f32x4){0.f, 0.f, 0.f, 0.f};
  for (int kt = 0; kt < 8; ++kt){
    int rb = cl * AGG_PAD + kt * 32 + kgrp * 8;
    bf16x8 ah = *(const bf16x8*)&s_hi[rb];
    bf16x8 al = *(const bf16x8*)&s_lo[rb];
#pragma unroll
    for (int nn = 0; nn < 2; ++nn){
      int nt = wid * 2 + nn;
      size_t wi = ((size_t)(kt * 8 + nt) * 64 + lane) * 8;    // Nc/16 = 8
      bf16x8 bh = *(const bf16x8*)(c_W2h + wi);
      bf16x8 bl = *(const bf16x8*)(c_W2l + wi);
      acc[nn] = __builtin_amdgcn_mfma_f32_16x16x32_bf16(ah, bh, acc[nn], 0, 0, 0);
      acc[nn] = __builtin_amdgcn_mfma_f32_16x16x32_bf16(ah, bl, acc[nn], 0, 0, 0);
      acc[nn] = __builtin_amdgcn_mfma_f32_16x16x32_bf16(al, bh, acc[nn], 0, 0, 0);
    }
  }

  float asv[2], adv[2];
#pragma unroll
  for (int nn = 0; nn < 2; ++nn){
    int col = (wid * 2 + nn) * 16 + cl;
    asv[nn] = c_as2f[col]; adv[nn] = c_ad2f[col];
  }
#pragma unroll
  for (int i = 0; i < 4; ++i){
    int row = nb + kgrp * 4 + i;
    float ps = 0.f, pd = 0.f;
#pragma unroll
    for (int nn = 0; nn < 2; ++nn){
      int col = (wid * 2 + nn) * 16 + cl;
      float v = acc[nn][i];
      g_h2b[(size_t)row * C_OUT + col] = f2bf(v);
      ps += v * asv[nn]; pd += v * adv[nn];
    }
    ps += __shfl_xor(ps, 1);  pd += __shfl_xor(pd, 1);
    ps += __shfl_xor(ps, 2);  pd += __shfl_xor(pd, 2);
    ps += __shfl_xor(ps, 4);  pd += __shfl_xor(pd, 4);
    ps += __shfl_xor(ps, 8);  pd += __shfl_xor(pd, 8);
    if (cl == 0){ s_ps[wid][kgrp * 4 + i] = ps; s_pd[wid][kgrp * 4 + i] = pd; }
  }
  __syncthreads();
  if (threadIdx.x < 16){
    int r = (int)threadIdx.x;
    g_alps2[nb + r] = s_ps[0][r] + s_ps[1][r] + s_ps[2][r] + s_ps[3][r];
    g_alpd2[nb + r] = s_pd[0][r] + s_pd[1][r] + s_pd[2][r] + s_pd[3][r];
  }
}

// ---------------- layer-2 softmax + aggregation: one wave per node (R1) ----------------
__global__ __launch_bounds__(256) void agg2_k(float* OUT){
  int lane = (int)(threadIdx.x & 63);
  int n = blockIdx.x * 4 + (int)(threadIdx.x >> 6);
  int len = g_cursor[n]; if (len > CAP) len = CAP;
  int i0 = n * CAP, i1 = i0 + len;
  float adn = g_alpd2[n];
  float dpart = 0.f;
  float a0 = 0.f, a1 = 0.f;
  const unsigned int* H1 = (const unsigned int*)g_h2b;

  { // implicit self-loop
    float es = g_alps2[n] + adn;
    es = (es > 0.f) ? es : NEG_SLOPE * es;
    float wself = __expf(es);
    if (lane == 0) dpart += wself;
    unsigned int p = H1[(size_t)n * 64 + lane];
    ACC2(p, wself)
  }

  for (int base = i0; base < i1; base += 64){
    int nv = i1 - base; if (nv > 64) nv = 64;
    int sv = 0; float wv = 0.f;
    if (lane < nv){
      sv = g_srcidx[base + lane];
      float e = g_alps2[sv] + adn;
      e = (e > 0.f) ? e : NEG_SLOPE * e;
      wv = __expf(e);
    }
    dpart += wv;
    int j = 0;
    for (; j + 8 <= nv; j += 8){
      int s0 = __shfl(sv, j),     s1 = __shfl(sv, j + 1);
      int s2 = __shfl(sv, j + 2), s3 = __shfl(sv, j + 3);
      int s4 = __shfl(sv, j + 4), s5 = __shfl(sv, j + 5);
      int s6 = __shfl(sv, j + 6), s7 = __shfl(sv, j + 7);
      float w0 = __shfl(wv, j),     w1 = __shfl(wv, j + 1);
      float w2 = __shfl(wv, j + 2), w3 = __shfl(wv, j + 3);
      float w4 = __shfl(wv, j + 4), w5 = __shfl(wv, j + 5);
      float w6 = __shfl(wv, j + 6), w7 = __shfl(wv, j + 7);
      unsigned int p0 = H1[(size_t)s0 * 64 + lane];
      unsigned int p1 = H1[(size_t)s1 * 64 + lane];
      unsigned int p2 = H1[(size_t)s2 * 64 + lane];
      unsigned int p3 = H1[(size_t)s3 * 64 + lane];
      unsigned int p4 = H1[(size_t)s4 * 64 + lane];
      unsigned int p5 = H1[(size_t)s5 * 64 + lane];
      unsigned int p6 = H1[(size_t)s6 * 64 + lane];
      unsigned int p7 = H1[(size_t)s7 * 64 + lane];
      ACC2(p0, w0) ACC2(p1, w1) ACC2(p2, w2) ACC2(p3, w3)
      ACC2(p4, w4) ACC2(p5, w5) ACC2(p6, w6) ACC2(p7, w7)
    }
    for (; j + 4 <= nv; j += 4){
      int s0 = __shfl(sv, j),     s1 = __shfl(sv, j + 1);
      int s2 = __shfl(sv, j + 2), s3 = __shfl(sv, j + 3);
      float w0 = __shfl(wv, j),     w1 = __shfl(wv, j + 1);
      float w2 = __shfl(wv, j + 2), w3 = __shfl(wv, j + 3);
      unsigned int p0 = H1[(size_t)s0 * 64 + lane];
      unsigned int p1 = H1[(size_t)s1 * 64 + lane];
      unsigned int p2 = H1[(size_t)s2 * 64 + lane];
      unsigned int p3 = H1[(size_t)s3 * 64 + lane];
      ACC2(p0, w0) ACC2(p1, w1) ACC2(p2, w2) ACC2(p3, w3)
    }
    for (; j < nv; ++j){
      int s = __shfl(sv, j);
      float w = __shfl(wv, j);
      unsigned int p = H1[(size_t)s * 64 + lane];
      ACC2(p, w)
    }
  }

  float den = dpart;
#pragma unroll
  for (int o = 32; o > 0; o >>= 1) den += __shfl_xor(den, o, 64);
  float inv = 1.f / den;

  float2 o;
  o.x = a0 * inv + c_b2f[2 * lane];
  o.y = a1 * inv + c_b2f[2 * lane + 1];
  ((float2*)OUT)[(size_t)n * 64 + lane] = o;
}

extern "C" void kernel_launch(void* const* d_in, const int* in_sizes, int n_in,
                              void* d_out, int out_size, void* d_ws, size_t ws_size,
                              hipStream_t stream){
  (void)in_sizes; (void)n_in; (void)out_size; (void)d_ws; (void)ws_size;
  const void* x  = d_in[0];
  const int*  ei = (const int*)d_in[1];
  float* out = (float*)d_out;

  Ptrs ps;
  ps.p[0] = d_in[2]; ps.p[1] = d_in[3]; ps.p[2] = d_in[4]; ps.p[3] = d_in[5];
  ps.p[4] = d_in[6]; ps.p[5] = d_in[7]; ps.p[6] = d_in[8]; ps.p[7] = d_in[9];

  prep_k<<<(PREP_T + 255) / 256, 256, 0, stream>>>((const unsigned int*)x, ei, ps);

  // ---- layer 1: gemm1 + edge scatter fused (independent work, one dispatch) ----
  gemm1_k<<<GEMM1_BLKS + SCAT_BLKS, 256, 0, stream>>>(x, ei);

  // ---- agg1 + gemm2 fused (row-aligned dependency -> in-block via LDS) ----
  aggemm_k<<<N_NODES / 16, 256, 0, stream>>>();

  // ---- layer 2 aggregation ----
  agg2_k<<<N_NODES / 4, 256, 0, stream>>>(out);
}